// Round 1
// baseline (30944.333 us; speedup 1.0000x reference)
//
#include <hip/hip_runtime.h>
#include <hip/hip_bf16.h>

#define T_STEPS 256
#define BS      64
#define NTOKEN  512
#define NINP    512
#define NHID    2048
#define NB      8
#define TOPKN   4
#define BSZ     256
#define ATT_OUT 340
#define DK      64
#define NH_C    4
#define DK_C    32
#define KSUM    (ATT_OUT + BSZ)   // 596
#define KV1     (DK + ATT_OUT)    // 404
#define GATES   1024

#define AGENT __HIP_MEMORY_SCOPE_AGENT

__device__ __forceinline__ float sigf(float x) { return 1.0f / (1.0f + expf(-x)); }
__device__ __forceinline__ float aload(const float* p) {
  return __hip_atomic_load(p, __ATOMIC_RELAXED, AGENT);
}
__device__ __forceinline__ void astore(float* p, float v) {
  __hip_atomic_store(p, v, __ATOMIC_RELAXED, AGENT);
}

// Monotone-counter grid barrier (relaxed agent atomics; data goes through
// agent-scope atomics so no L2-invalidating acquire fence is needed).
__device__ __forceinline__ void gbar(unsigned* cnt, unsigned* gen, unsigned nwg) {
  __syncthreads();  // compiler drains vmcnt/lgkmcnt of all threads before s_barrier
  if (threadIdx.x == 0) {
    asm volatile("s_waitcnt vmcnt(0) lgkmcnt(0)" ::: "memory");
    unsigned g = __hip_atomic_load(gen, __ATOMIC_RELAXED, AGENT);
    unsigned a = __hip_atomic_fetch_add(cnt, 1u, __ATOMIC_RELAXED, AGENT);
    if (((a + 1u) & (nwg - 1u)) == 0u) {   // nwg is power of two (256)
      __hip_atomic_store(gen, g + 1u, __ATOMIC_RELAXED, AGENT);
    } else {
      while (__hip_atomic_load(gen, __ATOMIC_RELAXED, AGENT) == g)
        __builtin_amdgcn_s_sleep(2);
    }
  }
  __syncthreads();
}

// ---------- Precompute 1: Wc = W_enc @ [Wk | Wv]  (512 x 404), bias_kv = b_enc @ [Wk|Wv]
__global__ void k_wc(const float* __restrict__ W_enc, const float* __restrict__ b_enc,
                     const float* __restrict__ Wk, const float* __restrict__ Wv,
                     float* __restrict__ Wc, float* __restrict__ bias_kv) {
  __shared__ float row[NINP];
  int d = blockIdx.x;  // 0..511 rows, 512 = bias row
  const float* src = (d < NTOKEN) ? (W_enc + (size_t)d * NINP) : b_enc;
  for (int i = threadIdx.x; i < NINP; i += blockDim.x) row[i] = src[i];
  __syncthreads();
  float* dst = (d < NTOKEN) ? (Wc + (size_t)d * KV1) : bias_kv;
  for (int j = threadIdx.x; j < KV1; j += blockDim.x) {
    float acc = 0.f;
    if (j < DK) {
      for (int p = 0; p < NINP; ++p) acc += row[p] * Wk[(size_t)p * DK + j];
    } else {
      int jj = j - DK;
      for (int p = 0; p < NINP; ++p) acc += row[p] * Wv[(size_t)p * ATT_OUT + jj];
    }
    dst[j] = acc;
  }
}

// ---------- Precompute 2: k1v1[t,b,:] = x[t,b,:] @ Wc + bias   (16384 x 404)
__global__ void k_kv(const float* __restrict__ x, const float* __restrict__ Wc,
                     const float* __restrict__ bias_kv, float* __restrict__ k1v1) {
  __shared__ float xl[8 * NTOKEN];
  int r0 = blockIdx.x * 8;  // 8 rows of (t*64+b)
  for (int i = threadIdx.x; i < 8 * NTOKEN; i += blockDim.x)
    xl[i] = x[(size_t)r0 * NTOKEN + i];
  __syncthreads();
  for (int j = threadIdx.x; j < KV1; j += blockDim.x) {
    float bj = bias_kv[j];
    float acc[8];
#pragma unroll
    for (int r = 0; r < 8; ++r) acc[r] = bj;
    for (int d = 0; d < NTOKEN; ++d) {
      float wc = Wc[(size_t)d * KV1 + j];
#pragma unroll
      for (int r = 0; r < 8; ++r) acc[r] += xl[r * NTOKEN + d] * wc;
    }
    for (int r = 0; r < 8; ++r) k1v1[(size_t)(r0 + r) * KV1 + j] = acc[r];
  }
}

// ---------- Precompute 3: gate-interleaved fused weights
// Wf[n][k][j*4+t] = (k<340 ? Wi[n][k][t*256+j] : Wh[n][k-340][t*256+j]),  bf likewise
__global__ void k_fuse(const float* __restrict__ Wi, const float* __restrict__ Wh,
                       const float* __restrict__ b_lstm,
                       float* __restrict__ Wf, float* __restrict__ bf) {
  int nk = blockIdx.x;  // 8*596
  int n = nk / KSUM, k = nk % KSUM;
  const float* src = (k < ATT_OUT) ? (Wi + ((size_t)n * ATT_OUT + k) * GATES)
                                   : (Wh + ((size_t)n * BSZ + (k - ATT_OUT)) * GATES);
  float* dst = Wf + ((size_t)n * KSUM + k) * GATES;
  for (int gc = threadIdx.x; gc < GATES; gc += blockDim.x) {
    int t = gc >> 8, j = gc & 255;
    dst[j * 4 + t] = src[gc];
  }
  if (k == 0) {
    for (int gc = threadIdx.x; gc < GATES; gc += blockDim.x) {
      int t = gc >> 8, j = gc & 255;
      bf[(size_t)n * GATES + j * 4 + t] = b_lstm[(size_t)n * GATES + gc];
    }
  }
}

// ---------- Main persistent RNN kernel: 256 WGs x 512 threads, 2 grid barriers/step
__global__ __launch_bounds__(512)
void k_rnn(const float* __restrict__ k1v1, const float* __restrict__ Wf,
           const float* __restrict__ bf, const float* __restrict__ Wq,
           const float* __restrict__ Wq_c, const float* __restrict__ Wk_c,
           const float* __restrict__ Wv_c, const float* __restrict__ Wo_c,
           float* h, float* c, float* hnew, float* cnew, float* zbuf,
           unsigned* bar, float* __restrict__ out) {
  const int w   = blockIdx.x;       // 256 WGs
  const int tid = threadIdx.x;      // 512
  const int n   = w & 7;            // block index -> XCD (w%8), weights L2-resident
  const int cs  = (w >> 3) & 7;     // cell slice (32 cells)
  const int bg  = w >> 6;           // batch group (16 b)
  const int bloc = tid >> 5;        // 0..15
  const int jj   = tid & 31;        // 0..31
  const int bG   = bg * 16 + bloc;
  const int jg   = cs * 32 + jj;    // cell within block

  unsigned* bar_cnt = bar;
  unsigned* bar_gen = bar + 1;

  __shared__ __align__(16) char smem[49152];

  const float scale_in = 0.125f;                  // 1/sqrt(64)
  const float scale_c  = 0.17677669529663687f;    // 1/sqrt(32)

  for (int t = 0; t < T_STEPS; ++t) {
    // ================= PHASE A: z/att1 + gates GEMM + LSTM pointwise =================
    float (*Al)[600] = (float(*)[600])smem;          // [16][600]: [0:340]=att1*v1, [340:596]=h
    float* k1l  = (float*)(smem + 38400);            // [16][64]
    float* ql   = (float*)(smem + 42496);            // [16][64]
    float* attl = (float*)(smem + 46592);            // [16]

    for (int i = tid; i < 16 * BSZ; i += 512) {
      int bb = i >> 8, d = i & 255;
      Al[bb][ATT_OUT + d] = aload(&h[(size_t)(bg * 16 + bb) * NHID + n * BSZ + d]);
    }
    for (int i = tid; i < 16 * DK; i += 512) {
      int bb = i >> 6, dk = i & 63;
      k1l[i] = k1v1[((size_t)t * BS + bg * 16 + bb) * KV1 + dk];
    }
    __syncthreads();
    {  // q = h_n @ Wq : 16x64 outputs, 2 per thread
      int bb = tid >> 5;
      int dk0 = (tid & 31) * 2;
      float a0 = 0.f, a1 = 0.f;
      const float* hb = &Al[bb][ATT_OUT];
      for (int d = 0; d < BSZ; ++d) {
        float hv = hb[d];
        const float* wq = &Wq[(size_t)d * DK + dk0];
        a0 += hv * wq[0];
        a1 += hv * wq[1];
      }
      ql[bb * 64 + dk0] = a0;
      ql[bb * 64 + dk0 + 1] = a1;
    }
    __syncthreads();
    if (tid < 16) {
      float acc = 0.f;
      for (int dd = 0; dd < DK; ++dd) acc += ql[tid * 64 + dd] * k1l[tid * 64 + dd];
      float z = acc * scale_in;
      attl[tid] = sigf(z);
      if (cs == 0) astore(&zbuf[(size_t)(bg * 16 + tid) * NB + n], z);
    }
    __syncthreads();
    for (int i = tid; i < 16 * ATT_OUT; i += 512) {
      int bb = i / ATT_OUT, v = i - bb * ATT_OUT;
      Al[bb][v] = attl[bb] * k1v1[((size_t)t * BS + bg * 16 + bb) * KV1 + DK + v];
    }
    __syncthreads();
    {  // GEMM: 1 cell x 1 batch per thread; 4 gates in float4; K = 596
      const float* Wr = Wf + (size_t)n * KSUM * GATES + (size_t)jg * 4;
      float4 acc = *(const float4*)(bf + (size_t)n * GATES + jg * 4);
      const float* Arow = Al[bloc];
      for (int k4 = 0; k4 < KSUM; k4 += 4) {
        float4 a4 = *(const float4*)(Arow + k4);
        const float* wp = Wr + (size_t)k4 * GATES;
        float4 w0 = *(const float4*)(wp);
        float4 w1 = *(const float4*)(wp + GATES);
        float4 w2 = *(const float4*)(wp + 2 * GATES);
        float4 w3 = *(const float4*)(wp + 3 * GATES);
        acc.x += a4.x * w0.x + a4.y * w1.x + a4.z * w2.x + a4.w * w3.x;
        acc.y += a4.x * w0.y + a4.y * w1.y + a4.z * w2.y + a4.w * w3.y;
        acc.z += a4.x * w0.z + a4.y * w1.z + a4.z * w2.z + a4.w * w3.z;
        acc.w += a4.x * w0.w + a4.y * w1.w + a4.z * w2.w + a4.w * w3.w;
      }
      float ig = sigf(acc.x), fg = sigf(acc.y), gg = tanhf(acc.z), og = sigf(acc.w);
      size_t idx = (size_t)bG * NHID + n * BSZ + jg;
      float cold = aload(&c[idx]);
      float cn = fg * cold + ig * gg;
      float hn = og * tanhf(cn);
      astore(&cnew[idx], cn);
      astore(&hnew[idx], hn);
    }
    gbar(bar_cnt, bar_gen, 256u);

    // ================= PHASE B (WGs 0..63, one batch each): topk + ctx attn + commit ==
    if (w < BS) {
      const int b = w;
      float* hnewl = (float*)smem;              // 2048
      float* holdl = (float*)(smem + 8192);     // 2048
      float* qcl   = (float*)(smem + 16384);    // 1024
      float* kcl   = (float*)(smem + 20480);
      float* vcl   = (float*)(smem + 24576);
      float* ocl   = (float*)(smem + 28672);
      float* acl   = (float*)(smem + 32768);    // [4][8][8]
      float* maskl = (float*)(smem + 33792);    // 8

      for (int i = tid; i < NHID; i += 512) {
        hnewl[i] = aload(&hnew[(size_t)b * NHID + i]);
        holdl[i] = aload(&h[(size_t)b * NHID + i]);
      }
      if (tid == 0) {
        // top-4 smallest null_att = sigmoid(-z); ties -> lowest index (matches lax.top_k)
        float natt[NB];
        for (int k = 0; k < NB; ++k)
          natt[k] = 1.f / (1.f + expf(aload(&zbuf[(size_t)b * NB + k])));
        bool used[NB] = {false, false, false, false, false, false, false, false};
        for (int k = 0; k < NB; ++k) maskl[k] = 0.f;
        for (int s = 0; s < TOPKN; ++s) {
          int best = -1; float bv = 0.f;
          for (int k = 0; k < NB; ++k)
            if (!used[k] && (best < 0 || natt[k] < bv)) { best = k; bv = natt[k]; }
          used[best] = true; maskl[best] = 1.f;
        }
      }
      __syncthreads();
      // qc/kc/vc = hnew @ W*_c  (3 x 8 x 128, K=256)
      for (int rep = 0; rep < 6; ++rep) {
        int o = rep * 512 + tid;
        int mat = o >> 10, r = o & 1023;
        int nn = r >> 7, ccol = r & 127;
        const float* W = (mat == 0) ? Wq_c : (mat == 1) ? Wk_c : Wv_c;
        const float* hv = &hnewl[nn * BSZ];
        float acc = 0.f;
        for (int d = 0; d < BSZ; ++d) acc += hv[d] * W[(size_t)d * 128 + ccol];
        float* dst = (mat == 0) ? qcl : (mat == 1) ? kcl : vcl;
        dst[r] = acc;
      }
      __syncthreads();
      if (tid < 32) {  // per (head, nq): 8-way softmax over m
        int hh = tid >> 3, nq = tid & 7;
        const float* qrow = &qcl[nq * 128 + hh * 32];
        float sc[NB]; float mx = -1e30f;
        for (int m = 0; m < NB; ++m) {
          const float* krow = &kcl[m * 128 + hh * 32];
          float acc = 0.f;
          for (int kk = 0; kk < DK_C; ++kk) acc += qrow[kk] * krow[kk];
          acc *= scale_c; sc[m] = acc; mx = fmaxf(mx, acc);
        }
        float sum = 0.f;
        for (int m = 0; m < NB; ++m) { sc[m] = expf(sc[m] - mx); sum += sc[m]; }
        float inv = 1.f / sum;
        for (int m = 0; m < NB; ++m) acl[(hh * 8 + nq) * 8 + m] = sc[m] * inv;
      }
      __syncthreads();
      for (int o = tid; o < 1024; o += 512) {  // oc = ac @ vc
        int nn = o >> 7, p = o & 127, hh = p >> 5;
        const float* arow = &acl[(hh * 8 + nn) * 8];
        float acc = 0.f;
        for (int m = 0; m < NB; ++m) acc += arow[m] * vcl[m * 128 + p];
        ocl[o] = acc;
      }
      __syncthreads();
      // commit: h/c for masked blocks, write out[t,b,:]
      for (int cell = tid; cell < NHID; cell += 512) {
        int nn = cell >> 8, j = cell & 255;
        float hv;
        if (maskl[nn] > 0.5f) {
          float add = 0.f;
          const float* oc = &ocl[nn * 128];
          for (int p = 0; p < 128; ++p) add += oc[p] * Wo_c[(size_t)p * BSZ + j];
          size_t idx = (size_t)b * NHID + cell;
          hv = hnewl[cell] + add;
          astore(&h[idx], hv);
          astore(&c[idx], aload(&cnew[idx]));
        } else {
          hv = holdl[cell];
        }
        out[((size_t)t * BS + b) * NHID + cell] = hv;
      }
    }
    gbar(bar_cnt, bar_gen, 256u);
  }
}

__global__ void k_sentinel(float* out) { out[0] = 12345.0f; }

extern "C" void kernel_launch(void* const* d_in, const int* in_sizes, int n_in,
                              void* d_out, int out_size, void* d_ws, size_t ws_size,
                              hipStream_t stream) {
  (void)in_sizes; (void)n_in; (void)out_size;
  const float* x      = (const float*)d_in[0];
  const float* h0     = (const float*)d_in[1];
  const float* c0     = (const float*)d_in[2];
  const float* W_enc  = (const float*)d_in[3];
  const float* b_enc  = (const float*)d_in[4];
  const float* Wq     = (const float*)d_in[5];
  const float* Wk     = (const float*)d_in[6];
  const float* Wv     = (const float*)d_in[7];
  const float* Wi     = (const float*)d_in[8];
  const float* Wh     = (const float*)d_in[9];
  const float* b_lstm = (const float*)d_in[10];
  const float* Wq_c   = (const float*)d_in[11];
  const float* Wk_c   = (const float*)d_in[12];
  const float* Wv_c   = (const float*)d_in[13];
  const float* Wo_c   = (const float*)d_in[14];
  float* out = (float*)d_out;

  float* ws = (float*)d_ws;
  size_t off = 0;
  auto alloc = [&](size_t nf) { float* p = ws + off; off += (nf + 15) & ~(size_t)15; return p; };
  float* k1v1 = alloc((size_t)T_STEPS * BS * KV1);
  float* Wc   = alloc((size_t)NTOKEN * KV1);
  float* bias = alloc(KV1);
  float* Wf   = alloc((size_t)NB * KSUM * GATES);
  float* bf   = alloc((size_t)NB * GATES);
  float* h    = alloc((size_t)BS * NHID);
  float* c    = alloc((size_t)BS * NHID);
  float* hnew = alloc((size_t)BS * NHID);
  float* cnew = alloc((size_t)BS * NHID);
  float* zbuf = alloc((size_t)BS * NB);
  unsigned* bar = (unsigned*)(ws + off); off += 16;

  if (ws_size < off * sizeof(float)) {  // loud failure instead of OOB corruption
    hipLaunchKernelGGL(k_sentinel, dim3(1), dim3(1), 0, stream, out);
    return;
  }

  hipMemsetAsync(bar, 0, 64, stream);
  hipMemcpyAsync(h, h0, (size_t)BS * NHID * sizeof(float), hipMemcpyDeviceToDevice, stream);
  hipMemcpyAsync(c, c0, (size_t)BS * NHID * sizeof(float), hipMemcpyDeviceToDevice, stream);

  hipLaunchKernelGGL(k_wc,   dim3(NTOKEN + 1),      dim3(128), 0, stream, W_enc, b_enc, Wk, Wv, Wc, bias);
  hipLaunchKernelGGL(k_kv,   dim3(T_STEPS * BS / 8), dim3(256), 0, stream, x, Wc, bias, k1v1);
  hipLaunchKernelGGL(k_fuse, dim3(NB * KSUM),       dim3(256), 0, stream, Wi, Wh, b_lstm, Wf, bf);
  hipLaunchKernelGGL(k_rnn,  dim3(256),             dim3(512), 0, stream,
                     k1v1, Wf, bf, Wq, Wq_c, Wk_c, Wv_c, Wo_c,
                     h, c, hnew, cnew, zbuf, bar, out);
}

// Round 2
// 19893.015 us; speedup vs baseline: 1.5555x; 1.5555x over previous
//
#include <hip/hip_runtime.h>
#include <hip/hip_bf16.h>

#define T_STEPS 256
#define BS      64
#define NTOKEN  512
#define NINP    512
#define NHID    2048
#define NB      8
#define TOPKN   4
#define BSZ     256
#define ATT_OUT 340
#define DK      64
#define NH_C    4
#define DK_C    32
#define KSUM    (ATT_OUT + BSZ)   // 596
#define KV1     (DK + ATT_OUT)    // 404
#define GATES   1024
#define NWG     256

#define AGENT __HIP_MEMORY_SCOPE_AGENT

__device__ __forceinline__ float sigf(float x) { return 1.0f / (1.0f + expf(-x)); }
__device__ __forceinline__ float aload(const float* p) {
  return __hip_atomic_load(p, __ATOMIC_RELAXED, AGENT);
}
__device__ __forceinline__ void astore(float* p, float v) {
  __hip_atomic_store(p, v, __ATOMIC_RELAXED, AGENT);
}
__device__ __forceinline__ unsigned aloadu(const unsigned* p) {
  return __hip_atomic_load(p, __ATOMIC_RELAXED, AGENT);
}
__device__ __forceinline__ void astoreu(unsigned* p, unsigned v) {
  __hip_atomic_store(p, v, __ATOMIC_RELAXED, AGENT);
}

// Distributed-arrival grid barrier: each WG stores epoch e to its own cacheline
// (no contention); master WG (255) polls all flags, releases via 8 per-XCD gen
// lines. All relaxed agent-scope; every thread drains vmcnt before arrival so
// its data stores are at the coherence point first.
__device__ __forceinline__ void gbar2(unsigned* flags, unsigned* gen, unsigned e) {
  const int w = blockIdx.x, tid = threadIdx.x;
  asm volatile("s_waitcnt vmcnt(0) lgkmcnt(0)" ::: "memory");
  __syncthreads();
  if (tid == 0) astoreu(&flags[w * 16], e);
  if (w == NWG - 1) {
    if (tid < NWG) {
      while (aloadu(&flags[tid * 16]) < e) __builtin_amdgcn_s_sleep(1);
    }
    __syncthreads();
    if (tid < 8) astoreu(&gen[tid * 16], e);
  } else {
    if (tid == 0) {
      while (aloadu(&gen[(w & 7) * 16]) < e) __builtin_amdgcn_s_sleep(1);
    }
  }
  __syncthreads();
}

// ---------- Precompute 1: Wc = W_enc @ [Wk | Wv]  (512 x 404), bias_kv = b_enc @ [Wk|Wv]
__global__ void k_wc(const float* __restrict__ W_enc, const float* __restrict__ b_enc,
                     const float* __restrict__ Wk, const float* __restrict__ Wv,
                     float* __restrict__ Wc, float* __restrict__ bias_kv) {
  __shared__ float row[NINP];
  int d = blockIdx.x;  // 0..511 rows, 512 = bias row
  const float* src = (d < NTOKEN) ? (W_enc + (size_t)d * NINP) : b_enc;
  for (int i = threadIdx.x; i < NINP; i += blockDim.x) row[i] = src[i];
  __syncthreads();
  float* dst = (d < NTOKEN) ? (Wc + (size_t)d * KV1) : bias_kv;
  for (int j = threadIdx.x; j < KV1; j += blockDim.x) {
    float acc = 0.f;
    if (j < DK) {
      for (int p = 0; p < NINP; ++p) acc += row[p] * Wk[(size_t)p * DK + j];
    } else {
      int jj = j - DK;
      for (int p = 0; p < NINP; ++p) acc += row[p] * Wv[(size_t)p * ATT_OUT + jj];
    }
    dst[j] = acc;
  }
}

// ---------- Precompute 2: k1v1[t,b,:] = x[t,b,:] @ Wc + bias   (16384 x 404)
__global__ void k_kv(const float* __restrict__ x, const float* __restrict__ Wc,
                     const float* __restrict__ bias_kv, float* __restrict__ k1v1) {
  __shared__ float xl[8 * NTOKEN];
  int r0 = blockIdx.x * 8;
  for (int i = threadIdx.x; i < 8 * NTOKEN; i += blockDim.x)
    xl[i] = x[(size_t)r0 * NTOKEN + i];
  __syncthreads();
  for (int j = threadIdx.x; j < KV1; j += blockDim.x) {
    float bj = bias_kv[j];
    float acc[8];
#pragma unroll
    for (int r = 0; r < 8; ++r) acc[r] = bj;
    for (int d = 0; d < NTOKEN; ++d) {
      float wc = Wc[(size_t)d * KV1 + j];
#pragma unroll
      for (int r = 0; r < 8; ++r) acc[r] += xl[r * NTOKEN + d] * wc;
    }
    for (int r = 0; r < 8; ++r) k1v1[(size_t)(r0 + r) * KV1 + j] = acc[r];
  }
}

// ---------- Precompute 3: gate-interleaved fused weights
__global__ void k_fuse(const float* __restrict__ Wi, const float* __restrict__ Wh,
                       const float* __restrict__ b_lstm,
                       float* __restrict__ Wf, float* __restrict__ bf) {
  int nk = blockIdx.x;  // 8*596
  int n = nk / KSUM, k = nk % KSUM;
  const float* src = (k < ATT_OUT) ? (Wi + ((size_t)n * ATT_OUT + k) * GATES)
                                   : (Wh + ((size_t)n * BSZ + (k - ATT_OUT)) * GATES);
  float* dst = Wf + ((size_t)n * KSUM + k) * GATES;
  for (int gc = threadIdx.x; gc < GATES; gc += blockDim.x) {
    int t = gc >> 8, j = gc & 255;
    dst[j * 4 + t] = src[gc];
  }
  if (k == 0) {
    for (int gc = threadIdx.x; gc < GATES; gc += blockDim.x) {
      int t = gc >> 8, j = gc & 255;
      bf[(size_t)n * GATES + j * 4 + t] = b_lstm[(size_t)n * GATES + gc];
    }
  }
}

// ---------- Main persistent RNN kernel: 256 WGs x 512 threads
// Phase A thread: 1 cell x 2 batches x half-K (32 FMA per 64B weight load).
__global__ __launch_bounds__(512)
void k_rnn(const float* __restrict__ k1v1, const float* __restrict__ Wf,
           const float* __restrict__ bf, const float* __restrict__ Wq,
           const float* __restrict__ Wq_c, const float* __restrict__ Wk_c,
           const float* __restrict__ Wv_c, const float* __restrict__ Wo_c,
           float* h, float* c, float* hnew, float* cnew, float* zbuf,
           unsigned* bar, float* __restrict__ out) {
  const int w   = blockIdx.x;       // 256 WGs: w = bg*64 + csg*8 + n
  const int tid = threadIdx.x;      // 512
  const int n   = w & 7;            // block -> XCD (w%8): weights L2-resident
  const int csg = (w >> 3) & 7;     // 32-cell slice
  const int bg  = w >> 6;           // batch group of 16
  const int jj  = tid & 31;         // cell within slice
  const int bp  = (tid >> 5) & 7;   // batch pair
  const int kh  = tid >> 8;         // K half: 0 -> [0,300), 1 -> [300,596)
  const int jg  = csg * 32 + jj;

  unsigned* flags = bar;
  unsigned* gen   = bar + 4096;

  __shared__ __align__(16) char smem[49152];

  for (int t = 0; t < T_STEPS; ++t) {
    // ================= PHASE A =================
    float (*Al)[600] = (float(*)[600])smem;        // [16][600]: [0:340)=att1*v1, [340:596)=h
    float* k1l  = (float*)(smem + 38400);          // [16][64]
    float* ql   = (float*)(smem + 42496);          // [16][64]
    float* red  = (float*)(smem + 38400);          // aliases k1l+ql (dead by GEMM)
    float* attl = (float*)(smem + 46592);          // [16]

#pragma unroll
    for (int r = 0; r < 8; ++r) {
      int i = r * 512 + tid;
      int bb = i >> 8, d = i & 255;
      Al[bb][ATT_OUT + d] = aload(&h[(size_t)(bg * 16 + bb) * NHID + n * BSZ + d]);
    }
    if (tid < 256) {
      int bb = tid >> 4, q = tid & 15;
      *(float4*)&k1l[bb * 64 + q * 4] =
          *(const float4*)&k1v1[((size_t)t * BS + bg * 16 + bb) * KV1 + q * 4];
    }
    __syncthreads();
    {  // q = h_n @ Wq : 16x64, 2 per thread
      int bb = tid >> 5, dk0 = (tid & 31) * 2;
      float a0 = 0.f, a1 = 0.f;
      const float* hb = &Al[bb][ATT_OUT];
#pragma unroll 4
      for (int d = 0; d < BSZ; ++d) {
        float hv = hb[d];
        float2 wq = *(const float2*)&Wq[(size_t)d * DK + dk0];
        a0 += hv * wq.x;
        a1 += hv * wq.y;
      }
      ql[bb * 64 + dk0] = a0;
      ql[bb * 64 + dk0 + 1] = a1;
    }
    __syncthreads();
    if (tid < 16) {
      float acc = 0.f;
      for (int dd = 0; dd < DK; ++dd) acc += ql[tid * 64 + dd] * k1l[tid * 64 + dd];
      float z = acc * 0.125f;
      attl[tid] = sigf(z);
      if (csg == 0) astore(&zbuf[(size_t)(bg * 16 + tid) * NB + n], z);
    }
    __syncthreads();
    for (int i = tid; i < 16 * 85; i += 512) {  // att1 * v1, float4
      int bb = i / 85, q = i - bb * 85;
      float4 v4 = *(const float4*)&k1v1[((size_t)t * BS + bg * 16 + bb) * KV1 + DK + q * 4];
      float a = attl[bb];
      float4 r;
      r.x = a * v4.x; r.y = a * v4.y; r.z = a * v4.z; r.w = a * v4.w;
      *(float4*)&Al[bb][q * 4] = r;
    }
    __syncthreads();
    {  // GEMM: 2 batches, half K
      const float* Wr = Wf + (size_t)n * KSUM * GATES + jg * 4;
      const int lb0 = bp * 2, lb1 = lb0 + 1;
      const float* A0 = Al[lb0];
      const float* A1 = Al[lb1];
      const int kbeg = kh ? 300 : 0;
      const int kend = kh ? 596 : 300;
      float4 acc0 = {0.f, 0.f, 0.f, 0.f}, acc1 = {0.f, 0.f, 0.f, 0.f};
#pragma unroll 8
      for (int k4 = kbeg; k4 < kend; k4 += 4) {
        float4 a0 = *(const float4*)(A0 + k4);
        float4 a1 = *(const float4*)(A1 + k4);
        const float* wp = Wr + (size_t)k4 * GATES;
        float4 w0 = *(const float4*)(wp);
        float4 w1 = *(const float4*)(wp + GATES);
        float4 w2 = *(const float4*)(wp + 2 * GATES);
        float4 w3 = *(const float4*)(wp + 3 * GATES);
        acc0.x += a0.x * w0.x + a0.y * w1.x + a0.z * w2.x + a0.w * w3.x;
        acc0.y += a0.x * w0.y + a0.y * w1.y + a0.z * w2.y + a0.w * w3.y;
        acc0.z += a0.x * w0.z + a0.y * w1.z + a0.z * w2.z + a0.w * w3.z;
        acc0.w += a0.x * w0.w + a0.y * w1.w + a0.z * w2.w + a0.w * w3.w;
        acc1.x += a1.x * w0.x + a1.y * w1.x + a1.z * w2.x + a1.w * w3.x;
        acc1.y += a1.x * w0.y + a1.y * w1.y + a1.z * w2.y + a1.w * w3.y;
        acc1.z += a1.x * w0.z + a1.y * w1.z + a1.z * w2.z + a1.w * w3.z;
        acc1.w += a1.x * w0.w + a1.y * w1.w + a1.z * w2.w + a1.w * w3.w;
      }
      if (kh) {
        *(float4*)&red[((jj * 8 + bp) * 2 + 0) * 4] = acc0;
        *(float4*)&red[((jj * 8 + bp) * 2 + 1) * 4] = acc1;
      }
      __syncthreads();
      if (!kh) {
        float4 r0 = *(float4*)&red[((jj * 8 + bp) * 2 + 0) * 4];
        float4 r1 = *(float4*)&red[((jj * 8 + bp) * 2 + 1) * 4];
        float4 bia = *(const float4*)&bf[(size_t)n * GATES + jg * 4];
        float4 g0, g1;
        g0.x = acc0.x + r0.x + bia.x; g0.y = acc0.y + r0.y + bia.y;
        g0.z = acc0.z + r0.z + bia.z; g0.w = acc0.w + r0.w + bia.w;
        g1.x = acc1.x + r1.x + bia.x; g1.y = acc1.y + r1.y + bia.y;
        g1.z = acc1.z + r1.z + bia.z; g1.w = acc1.w + r1.w + bia.w;
        size_t i0 = (size_t)(bg * 16 + lb0) * NHID + n * BSZ + jg;
        size_t i1 = (size_t)(bg * 16 + lb1) * NHID + n * BSZ + jg;
        {
          float ig = sigf(g0.x), fg = sigf(g0.y), gg = tanhf(g0.z), og = sigf(g0.w);
          float cn = fg * aload(&c[i0]) + ig * gg;
          float hn = og * tanhf(cn);
          astore(&cnew[i0], cn);
          astore(&hnew[i0], hn);
        }
        {
          float ig = sigf(g1.x), fg = sigf(g1.y), gg = tanhf(g1.z), og = sigf(g1.w);
          float cn = fg * aload(&c[i1]) + ig * gg;
          float hn = og * tanhf(cn);
          astore(&cnew[i1], cn);
          astore(&hnew[i1], hn);
        }
      }
    }
    gbar2(flags, gen, 2u * t + 1u);

    // ================= PHASE B (WGs 0..63, one batch each) =================
    if (w < BS) {
      const int b = w;
      float* hnewl = (float*)smem;              // 2048
      float* holdl = (float*)(smem + 8192);     // 2048
      float* qcl   = (float*)(smem + 16384);    // 1024
      float* kcl   = (float*)(smem + 20480);
      float* vcl   = (float*)(smem + 24576);
      float* ocl   = (float*)(smem + 28672);
      float* acl   = (float*)(smem + 32768);    // [4][8][8]
      float* maskl = (float*)(smem + 33792);    // 8

#pragma unroll
      for (int r = 0; r < 4; ++r) {
        int i = r * 512 + tid;
        hnewl[i] = aload(&hnew[(size_t)b * NHID + i]);
        holdl[i] = aload(&h[(size_t)b * NHID + i]);
      }
      if (tid == 0) {
        // top-4 largest z (== smallest sigmoid(-z)); ties -> lowest index
        float zv[NB];
        for (int k = 0; k < NB; ++k) zv[k] = aload(&zbuf[(size_t)b * NB + k]);
        bool used[NB] = {};
        for (int k = 0; k < NB; ++k) maskl[k] = 0.f;
        for (int s = 0; s < TOPKN; ++s) {
          int best = -1; float bv = 0.f;
          for (int k = 0; k < NB; ++k)
            if (!used[k] && (best < 0 || zv[k] > bv)) { best = k; bv = zv[k]; }
          used[best] = true; maskl[best] = 1.f;
        }
      }
      __syncthreads();
      // qc/kc/vc = hnew @ W*_c : 768 float4 outputs
      for (int o = tid; o < 768; o += 512) {
        int mat = o >> 8, r = o & 255;
        int nn = r >> 5, c0 = (r & 31) * 4;
        const float* W = (mat == 0) ? Wq_c : (mat == 1) ? Wk_c : Wv_c;
        const float* hv = &hnewl[nn * BSZ];
        float4 acc = {0.f, 0.f, 0.f, 0.f};
#pragma unroll 4
        for (int d = 0; d < BSZ; ++d) {
          float hb = hv[d];
          float4 w4 = *(const float4*)&W[(size_t)d * 128 + c0];
          acc.x += hb * w4.x; acc.y += hb * w4.y;
          acc.z += hb * w4.z; acc.w += hb * w4.w;
        }
        float* dst = (mat == 0) ? qcl : (mat == 1) ? kcl : vcl;
        *(float4*)&dst[r * 4] = acc;
      }
      __syncthreads();
      if (tid < 32) {  // per (head, nq): softmax over 8 blocks
        int hh = tid >> 3, nq = tid & 7;
        const float* qrow = &qcl[nq * 128 + hh * 32];
        float sc[NB]; float mx = -1e30f;
        for (int m = 0; m < NB; ++m) {
          const float* krow = &kcl[m * 128 + hh * 32];
          float acc = 0.f;
#pragma unroll
          for (int kk = 0; kk < DK_C; ++kk) acc += qrow[kk] * krow[kk];
          acc *= 0.17677669529663687f; sc[m] = acc; mx = fmaxf(mx, acc);
        }
        float sum = 0.f;
        for (int m = 0; m < NB; ++m) { sc[m] = expf(sc[m] - mx); sum += sc[m]; }
        float inv = 1.f / sum;
        for (int m = 0; m < NB; ++m) acl[(hh * 8 + nq) * 8 + m] = sc[m] * inv;
      }
      __syncthreads();
      if (tid < 256) {  // oc = ac @ vc : 256 float4
        int nn = tid >> 5, c4 = tid & 31, c0 = c4 * 4, hh = c4 >> 3;
        const float* arow = &acl[(hh * 8 + nn) * 8];
        float4 acc = {0.f, 0.f, 0.f, 0.f};
#pragma unroll
        for (int m = 0; m < NB; ++m) {
          float a = arow[m];
          float4 v4 = *(const float4*)&vcl[m * 128 + c0];
          acc.x += a * v4.x; acc.y += a * v4.y;
          acc.z += a * v4.z; acc.w += a * v4.w;
        }
        *(float4*)&ocl[tid * 4] = acc;
      }
      __syncthreads();
      {  // commit: one float4 of cells per thread
        int nn = tid >> 6, j0 = (tid & 63) * 4;
        int li = nn * BSZ + j0;
        size_t base = (size_t)b * NHID + li;
        float4 hv4;
        if (maskl[nn] > 0.5f) {
          const float* oc = &ocl[nn * 128];
          float4 add = {0.f, 0.f, 0.f, 0.f};
#pragma unroll 4
          for (int p = 0; p < 128; ++p) {
            float o = oc[p];
            float4 w4 = *(const float4*)&Wo_c[(size_t)p * BSZ + j0];
            add.x += o * w4.x; add.y += o * w4.y;
            add.z += o * w4.z; add.w += o * w4.w;
          }
          hv4.x = hnewl[li] + add.x; hv4.y = hnewl[li + 1] + add.y;
          hv4.z = hnewl[li + 2] + add.z; hv4.w = hnewl[li + 3] + add.w;
          astore(&h[base], hv4.x);     astore(&h[base + 1], hv4.y);
          astore(&h[base + 2], hv4.z); astore(&h[base + 3], hv4.w);
          astore(&c[base], aload(&cnew[base]));
          astore(&c[base + 1], aload(&cnew[base + 1]));
          astore(&c[base + 2], aload(&cnew[base + 2]));
          astore(&c[base + 3], aload(&cnew[base + 3]));
        } else {
          hv4 = *(float4*)&holdl[li];
        }
        *(float4*)&out[((size_t)t * BS + b) * NHID + li] = hv4;
      }
    }
    gbar2(flags, gen, 2u * t + 2u);
  }
}

__global__ void k_sentinel(float* out) { out[0] = 12345.0f; }

extern "C" void kernel_launch(void* const* d_in, const int* in_sizes, int n_in,
                              void* d_out, int out_size, void* d_ws, size_t ws_size,
                              hipStream_t stream) {
  (void)in_sizes; (void)n_in; (void)out_size;
  const float* x      = (const float*)d_in[0];
  const float* h0     = (const float*)d_in[1];
  const float* c0     = (const float*)d_in[2];
  const float* W_enc  = (const float*)d_in[3];
  const float* b_enc  = (const float*)d_in[4];
  const float* Wq     = (const float*)d_in[5];
  const float* Wk     = (const float*)d_in[6];
  const float* Wv     = (const float*)d_in[7];
  const float* Wi     = (const float*)d_in[8];
  const float* Wh     = (const float*)d_in[9];
  const float* b_lstm = (const float*)d_in[10];
  const float* Wq_c   = (const float*)d_in[11];
  const float* Wk_c   = (const float*)d_in[12];
  const float* Wv_c   = (const float*)d_in[13];
  const float* Wo_c   = (const float*)d_in[14];
  float* out = (float*)d_out;

  float* ws = (float*)d_ws;
  size_t off = 0;
  auto alloc = [&](size_t nf) { float* p = ws + off; off += (nf + 15) & ~(size_t)15; return p; };
  float* k1v1 = alloc((size_t)T_STEPS * BS * KV1);
  float* Wc   = alloc((size_t)NTOKEN * KV1);
  float* bias = alloc(KV1);
  float* Wf   = alloc((size_t)NB * KSUM * GATES);
  float* bf   = alloc((size_t)NB * GATES);
  float* h    = alloc((size_t)BS * NHID);
  float* c    = alloc((size_t)BS * NHID);
  float* hnew = alloc((size_t)BS * NHID);
  float* cnew = alloc((size_t)BS * NHID);
  float* zbuf = alloc((size_t)BS * NB);
  // barrier region: 256 flag lines (16 u32 each) + 8 gen lines
  unsigned* bar = (unsigned*)(ws + off); off += 4096 + 128 + 16;

  if (ws_size < off * sizeof(float)) {  // loud failure instead of OOB corruption
    hipLaunchKernelGGL(k_sentinel, dim3(1), dim3(1), 0, stream, out);
    return;
  }

  hipMemsetAsync(bar, 0, (4096 + 128) * sizeof(unsigned), stream);
  hipMemcpyAsync(h, h0, (size_t)BS * NHID * sizeof(float), hipMemcpyDeviceToDevice, stream);
  hipMemcpyAsync(c, c0, (size_t)BS * NHID * sizeof(float), hipMemcpyDeviceToDevice, stream);

  hipLaunchKernelGGL(k_wc,   dim3(NTOKEN + 1),       dim3(128), 0, stream, W_enc, b_enc, Wk, Wv, Wc, bias);
  hipLaunchKernelGGL(k_kv,   dim3(T_STEPS * BS / 8), dim3(256), 0, stream, x, Wc, bias, k1v1);
  hipLaunchKernelGGL(k_fuse, dim3(NB * KSUM),        dim3(256), 0, stream, Wi, Wh, b_lstm, Wf, bf);
  hipLaunchKernelGGL(k_rnn,  dim3(NWG),              dim3(512), 0, stream,
                     k1v1, Wf, bf, Wq, Wq_c, Wk_c, Wv_c, Wo_c,
                     h, c, hnew, cnew, zbuf, bar, out);
}

// Round 4
// 18319.806 us; speedup vs baseline: 1.6891x; 1.0859x over previous
//
#include <hip/hip_runtime.h>
#include <hip/hip_bf16.h>

#define T_STEPS 256
#define BS      64
#define NTOKEN  512
#define NINP    512
#define NHID    2048
#define NB      8
#define TOPKN   4
#define BSZ     256
#define ATT_OUT 340
#define DK      64
#define NH_C    4
#define DK_C    32
#define KSUM    (ATT_OUT + BSZ)   // 596
#define KV1     (DK + ATT_OUT)    // 404
#define GATES   1024
#define NWG     256

#define AGENT __HIP_MEMORY_SCOPE_AGENT

__device__ __forceinline__ float sigf(float x) { return 1.0f / (1.0f + expf(-x)); }
__device__ __forceinline__ float aload(const float* p) {
  return __hip_atomic_load(p, __ATOMIC_RELAXED, AGENT);
}
__device__ __forceinline__ void astore(float* p, float v) {
  __hip_atomic_store(p, v, __ATOMIC_RELAXED, AGENT);
}
__device__ __forceinline__ unsigned aloadu(const unsigned* p) {
  return __hip_atomic_load(p, __ATOMIC_RELAXED, AGENT);
}
__device__ __forceinline__ void astoreu(unsigned* p, unsigned v) {
  __hip_atomic_store(p, v, __ATOMIC_RELAXED, AGENT);
}

// Distributed-arrival grid barrier (round-2 proven).
__device__ __forceinline__ void gbar2(unsigned* flags, unsigned* gen, unsigned e) {
  const int w = blockIdx.x, tid = threadIdx.x;
  asm volatile("s_waitcnt vmcnt(0) lgkmcnt(0)" ::: "memory");
  __syncthreads();
  if (tid == 0) astoreu(&flags[w * 16], e);
  if (w == NWG - 1) {
    if (tid < NWG) {
      while (aloadu(&flags[tid * 16]) < e) __builtin_amdgcn_s_sleep(1);
    }
    __syncthreads();
    if (tid < 8) astoreu(&gen[tid * 16], e);
  } else {
    if (tid == 0) {
      while (aloadu(&gen[(w & 7) * 16]) < e) __builtin_amdgcn_s_sleep(1);
    }
  }
  __syncthreads();
}

// ---------- Precompute 1: Wc = W_enc @ [Wk | Wv]  (512 x 404), bias_kv = b_enc @ [Wk|Wv]
__global__ void k_wc(const float* __restrict__ W_enc, const float* __restrict__ b_enc,
                     const float* __restrict__ Wk, const float* __restrict__ Wv,
                     float* __restrict__ Wc, float* __restrict__ bias_kv) {
  __shared__ float row[NINP];
  int d = blockIdx.x;  // 0..511 rows, 512 = bias row
  const float* src = (d < NTOKEN) ? (W_enc + (size_t)d * NINP) : b_enc;
  for (int i = threadIdx.x; i < NINP; i += blockDim.x) row[i] = src[i];
  __syncthreads();
  float* dst = (d < NTOKEN) ? (Wc + (size_t)d * KV1) : bias_kv;
  for (int j = threadIdx.x; j < KV1; j += blockDim.x) {
    float acc = 0.f;
    if (j < DK) {
      for (int p = 0; p < NINP; ++p) acc += row[p] * Wk[(size_t)p * DK + j];
    } else {
      int jj = j - DK;
      for (int p = 0; p < NINP; ++p) acc += row[p] * Wv[(size_t)p * ATT_OUT + jj];
    }
    dst[j] = acc;
  }
}

// ---------- Precompute 2: k1v1[t,b,:] = x[t,b,:] @ Wc + bias   (16384 x 404)
__global__ void k_kv(const float* __restrict__ x, const float* __restrict__ Wc,
                     const float* __restrict__ bias_kv, float* __restrict__ k1v1) {
  __shared__ float xl[8 * NTOKEN];
  int r0 = blockIdx.x * 8;
  for (int i = threadIdx.x; i < 8 * NTOKEN; i += blockDim.x)
    xl[i] = x[(size_t)r0 * NTOKEN + i];
  __syncthreads();
  for (int j = threadIdx.x; j < KV1; j += blockDim.x) {
    float bj = bias_kv[j];
    float acc[8];
#pragma unroll
    for (int r = 0; r < 8; ++r) acc[r] = bj;
    for (int d = 0; d < NTOKEN; ++d) {
      float wc = Wc[(size_t)d * KV1 + j];
#pragma unroll
      for (int r = 0; r < 8; ++r) acc[r] += xl[r * NTOKEN + d] * wc;
    }
    for (int r = 0; r < 8; ++r) k1v1[(size_t)(r0 + r) * KV1 + j] = acc[r];
  }
}

// ---------- Precompute 3: gate-interleaved fused weights
// Wf[n][k][j*4+t] = (k<340 ? Wi[n][k][t*256+j] : Wh[n][k-340][t*256+j]),  bf likewise
__global__ void k_fuse(const float* __restrict__ Wi, const float* __restrict__ Wh,
                       const float* __restrict__ b_lstm,
                       float* __restrict__ Wf, float* __restrict__ bf) {
  int nk = blockIdx.x;  // 8*596
  int n = nk / KSUM, k = nk % KSUM;
  const float* src = (k < ATT_OUT) ? (Wi + ((size_t)n * ATT_OUT + k) * GATES)
                                   : (Wh + ((size_t)n * BSZ + (k - ATT_OUT)) * GATES);
  float* dst = Wf + ((size_t)n * KSUM + k) * GATES;
  for (int gc = threadIdx.x; gc < GATES; gc += blockDim.x) {
    int t = gc >> 8, j = gc & 255;
    dst[j * 4 + t] = src[gc];
  }
  if (k == 0) {
    for (int gc = threadIdx.x; gc < GATES; gc += blockDim.x) {
      int t = gc >> 8, j = gc & 255;
      bf[(size_t)n * GATES + j * 4 + t] = b_lstm[(size_t)n * GATES + gc];
    }
  }
}

// ---------- Main persistent RNN kernel: 256 WGs x 512 threads
// Phase A GEMM: thread = (kh4, bo, jj) -> 4 batches x 4 gates, K interleaved 4-way.
// 64 FMAs per 4 independent global weight loads; 4-way LDS reduction finishes LSTM.
__global__ __launch_bounds__(512)
void k_rnn(const float* __restrict__ k1v1, const float* __restrict__ Wf,
           const float* __restrict__ bf, const float* __restrict__ Wq,
           const float* __restrict__ Wq_c, const float* __restrict__ Wk_c,
           const float* __restrict__ Wv_c, const float* __restrict__ Wo_c,
           float* h, float* c, float* hnew, float* cnew, float* zbuf,
           unsigned* bar, float* __restrict__ out) {
  const int w   = blockIdx.x;       // 256 WGs: w = bg*64 + csg*8 + n
  const int tid = threadIdx.x;      // 512
  const int n   = w & 7;            // block -> XCD (w%8), weights L2-resident
  const int csg = (w >> 3) & 7;     // 32-cell slice
  const int bg  = w >> 6;           // batch group of 16
  const int jj  = tid & 31;         // cell within slice
  const int bo  = (tid >> 5) & 3;   // batch quad (4 batches)
  const int kh4 = tid >> 7;         // K interleave class (k4 % 16 == kh4*4)
  const int jg  = csg * 32 + jj;

  unsigned* flags = bar;
  unsigned* gen   = bar + 4096;

  __shared__ __align__(16) char smem[49152];

  for (int t = 0; t < T_STEPS; ++t) {
    // ================= PHASE A =================
    float (*Al)[600] = (float(*)[600])smem;          // [16][600]: [0:340)=att1*v1, [340:596)=h
    float* k1l  = (float*)(smem + 38400);            // [16][64]
    float* ql   = (float*)(smem + 42496);            // [16][64]
    float* attl = (float*)(smem + 46592);            // [16]

#pragma unroll
    for (int r = 0; r < 8; ++r) {
      int i = r * 512 + tid;
      int bb = i >> 8, d = i & 255;
      Al[bb][ATT_OUT + d] = aload(&h[(size_t)(bg * 16 + bb) * NHID + n * BSZ + d]);
    }
    if (tid < 256) {
      int bb = tid >> 4, q = tid & 15;
      *(float4*)&k1l[bb * 64 + q * 4] =
          *(const float4*)&k1v1[((size_t)t * BS + bg * 16 + bb) * KV1 + q * 4];
    }
    __syncthreads();
    {  // q = h_n @ Wq : 16x64, 2 per thread
      int bb = tid >> 5, dk0 = (tid & 31) * 2;
      float a0 = 0.f, a1 = 0.f;
      const float* hb = &Al[bb][ATT_OUT];
#pragma unroll 4
      for (int d = 0; d < BSZ; ++d) {
        float hv = hb[d];
        float2 wq = *(const float2*)&Wq[(size_t)d * DK + dk0];
        a0 += hv * wq.x;
        a1 += hv * wq.y;
      }
      ql[bb * 64 + dk0] = a0;
      ql[bb * 64 + dk0 + 1] = a1;
    }
    __syncthreads();
    if (tid < 16) {
      float acc = 0.f;
      for (int dd = 0; dd < DK; ++dd) acc += ql[tid * 64 + dd] * k1l[tid * 64 + dd];
      float z = acc * 0.125f;
      attl[tid] = sigf(z);
      if (csg == 0) astore(&zbuf[(size_t)(bg * 16 + tid) * NB + n], z);
    }
    __syncthreads();
    for (int i = tid; i < 16 * 85; i += 512) {  // att1 * v1, float4
      int bb = i / 85, q = i - bb * 85;
      float4 v4 = *(const float4*)&k1v1[((size_t)t * BS + bg * 16 + bb) * KV1 + DK + q * 4];
      float a = attl[bb];
      float4 r;
      r.x = a * v4.x; r.y = a * v4.y; r.z = a * v4.z; r.w = a * v4.w;
      *(float4*)&Al[bb][q * 4] = r;
    }
    __syncthreads();

    // ===== GEMM: 4 batches x 4 gates per thread, K interleaved 4-way =====
    float4 acc[4];
#pragma unroll
    for (int i = 0; i < 4; ++i) acc[i] = make_float4(0.f, 0.f, 0.f, 0.f);
    {
      const float* Wr = Wf + (size_t)n * KSUM * GATES + jg * 4;
      const float* A0 = Al[bo * 4 + 0];
      const float* A1 = Al[bo * 4 + 1];
      const float* A2 = Al[bo * 4 + 2];
      const float* A3 = Al[bo * 4 + 3];
#pragma unroll 4
      for (int k4 = kh4 * 4; k4 < KSUM; k4 += 16) {
        const float* wp = Wr + (size_t)k4 * GATES;
        float4 w0 = *(const float4*)(wp);
        float4 w1 = *(const float4*)(wp + GATES);
        float4 w2 = *(const float4*)(wp + 2 * GATES);
        float4 w3 = *(const float4*)(wp + 3 * GATES);
        float4 a0 = *(const float4*)(A0 + k4);
        float4 a1 = *(const float4*)(A1 + k4);
        float4 a2 = *(const float4*)(A2 + k4);
        float4 a3 = *(const float4*)(A3 + k4);
        acc[0].x += a0.x * w0.x + a0.y * w1.x + a0.z * w2.x + a0.w * w3.x;
        acc[0].y += a0.x * w0.y + a0.y * w1.y + a0.z * w2.y + a0.w * w3.y;
        acc[0].z += a0.x * w0.z + a0.y * w1.z + a0.z * w2.z + a0.w * w3.z;
        acc[0].w += a0.x * w0.w + a0.y * w1.w + a0.z * w2.w + a0.w * w3.w;
        acc[1].x += a1.x * w0.x + a1.y * w1.x + a1.z * w2.x + a1.w * w3.x;
        acc[1].y += a1.x * w0.y + a1.y * w1.y + a1.z * w2.y + a1.w * w3.y;
        acc[1].z += a1.x * w0.z + a1.y * w1.z + a1.z * w2.z + a1.w * w3.z;
        acc[1].w += a1.x * w0.w + a1.y * w1.w + a1.z * w2.w + a1.w * w3.w;
        acc[2].x += a2.x * w0.x + a2.y * w1.x + a2.z * w2.x + a2.w * w3.x;
        acc[2].y += a2.x * w0.y + a2.y * w1.y + a2.z * w2.y + a2.w * w3.y;
        acc[2].z += a2.x * w0.z + a2.y * w1.z + a2.z * w2.z + a2.w * w3.z;
        acc[2].w += a2.x * w0.w + a2.y * w1.w + a2.z * w2.w + a2.w * w3.w;
        acc[3].x += a3.x * w0.x + a3.y * w1.x + a3.z * w2.x + a3.w * w3.x;
        acc[3].y += a3.x * w0.y + a3.y * w1.y + a3.z * w2.y + a3.w * w3.y;
        acc[3].z += a3.x * w0.z + a3.y * w1.z + a3.z * w2.z + a3.w * w3.z;
        acc[3].w += a3.x * w0.w + a3.y * w1.w + a3.z * w2.w + a3.w * w3.w;
      }
    }
    __syncthreads();  // Al dead; red aliases it

    // ===== 4-way kh reduction + LSTM pointwise (512 threads, one (b,cell) each) =====
    {
      float4* red4 = (float4*)smem;  // 32KB over dead Al
#pragma unroll
      for (int i = 0; i < 4; ++i)
        red4[(tid << 2) + ((i ^ jj) & 3)] = acc[i];
      __syncthreads();
      {
        const int jjr = tid & 31, b = tid >> 5;     // b 0..15
        float4 g4 = make_float4(0.f, 0.f, 0.f, 0.f);
#pragma unroll
        for (int kh = 0; kh < 4; ++kh) {
          float4 v = red4[(((kh << 7) + ((b >> 2) << 5) + jjr) << 2) + ((b ^ jjr) & 3)];
          g4.x += v.x; g4.y += v.y; g4.z += v.z; g4.w += v.w;
        }
        const int jgr = csg * 32 + jjr;
        float4 bia = *(const float4*)&bf[(size_t)n * GATES + jgr * 4];
        float ig = sigf(g4.x + bia.x), fg = sigf(g4.y + bia.y);
        float gg = tanhf(g4.z + bia.z), og = sigf(g4.w + bia.w);
        size_t idx = (size_t)(bg * 16 + b) * NHID + n * BSZ + jgr;
        float cn = fg * aload(&c[idx]) + ig * gg;
        float hn = og * tanhf(cn);
        astore(&cnew[idx], cn);
        astore(&hnew[idx], hn);
      }
    }
    gbar2(flags, gen, 2u * t + 1u);

    // ================= PHASE B (WGs 0..63, one batch each) =================
    if (w < BS) {
      const int b = w;
      float* hnewl = (float*)smem;              // 2048
      float* holdl = (float*)(smem + 8192);     // 2048
      float* qcl   = (float*)(smem + 16384);    // 1024
      float* kcl   = (float*)(smem + 20480);
      float* vcl   = (float*)(smem + 24576);
      float* ocl   = (float*)(smem + 28672);
      float* acl   = (float*)(smem + 32768);    // [4][8][8]
      float* maskl = (float*)(smem + 33792);    // 8

#pragma unroll
      for (int r = 0; r < 4; ++r) {
        int i = r * 512 + tid;
        hnewl[i] = aload(&hnew[(size_t)b * NHID + i]);
        holdl[i] = aload(&h[(size_t)b * NHID + i]);
      }
      if (tid == 0) {
        // top-4 largest z (== smallest sigmoid(-z)); ties -> lowest index
        float zv[NB];
        for (int k = 0; k < NB; ++k) zv[k] = aload(&zbuf[(size_t)b * NB + k]);
        bool used[NB] = {};
        for (int k = 0; k < NB; ++k) maskl[k] = 0.f;
        for (int s = 0; s < TOPKN; ++s) {
          int best = -1; float bv = 0.f;
          for (int k = 0; k < NB; ++k)
            if (!used[k] && (best < 0 || zv[k] > bv)) { best = k; bv = zv[k]; }
          used[best] = true; maskl[best] = 1.f;
        }
      }
      __syncthreads();
      // qc/kc/vc = hnew @ W*_c : 768 float4 outputs
      for (int o = tid; o < 768; o += 512) {
        int mat = o >> 8, r = o & 255;
        int nn = r >> 5, c0 = (r & 31) * 4;
        const float* W = (mat == 0) ? Wq_c : (mat == 1) ? Wk_c : Wv_c;
        const float* hv = &hnewl[nn * BSZ];
        float4 a4 = make_float4(0.f, 0.f, 0.f, 0.f);
#pragma unroll 4
        for (int d = 0; d < BSZ; ++d) {
          float hb = hv[d];
          float4 w4 = *(const float4*)&W[(size_t)d * 128 + c0];
          a4.x += hb * w4.x; a4.y += hb * w4.y;
          a4.z += hb * w4.z; a4.w += hb * w4.w;
        }
        float* dst = (mat == 0) ? qcl : (mat == 1) ? kcl : vcl;
        *(float4*)&dst[r * 4] = a4;
      }
      __syncthreads();
      if (tid < 32) {  // per (head, nq): softmax over 8 blocks
        int hh = tid >> 3, nq = tid & 7;
        const float* qrow = &qcl[nq * 128 + hh * 32];
        float sc[NB]; float mx = -1e30f;
        for (int m = 0; m < NB; ++m) {
          const float* krow = &kcl[m * 128 + hh * 32];
          float a = 0.f;
#pragma unroll
          for (int kk = 0; kk < DK_C; ++kk) a += qrow[kk] * krow[kk];
          a *= 0.17677669529663687f; sc[m] = a; mx = fmaxf(mx, a);
        }
        float sum = 0.f;
        for (int m = 0; m < NB; ++m) { sc[m] = expf(sc[m] - mx); sum += sc[m]; }
        float inv = 1.f / sum;
        for (int m = 0; m < NB; ++m) acl[(hh * 8 + nq) * 8 + m] = sc[m] * inv;
      }
      __syncthreads();
      if (tid < 256) {  // oc = ac @ vc : 256 float4
        int nn = tid >> 5, c4 = tid & 31, c0 = c4 * 4, hh = c4 >> 3;
        const float* arow = &acl[(hh * 8 + nn) * 8];
        float4 a4 = make_float4(0.f, 0.f, 0.f, 0.f);
#pragma unroll
        for (int m = 0; m < NB; ++m) {
          float a = arow[m];
          float4 v4 = *(const float4*)&vcl[m * 128 + c0];
          a4.x += a * v4.x; a4.y += a * v4.y;
          a4.z += a * v4.z; a4.w += a * v4.w;
        }
        *(float4*)&ocl[tid * 4] = a4;
      }
      __syncthreads();
      {  // commit: one float4 of cells per thread
        int nn = tid >> 6, j0 = (tid & 63) * 4;
        int li = nn * BSZ + j0;
        size_t base = (size_t)b * NHID + li;
        float4 hv4;
        if (maskl[nn] > 0.5f) {
          const float* oc = &ocl[nn * 128];
          float4 add = make_float4(0.f, 0.f, 0.f, 0.f);
#pragma unroll 4
          for (int p = 0; p < 128; ++p) {
            float o = oc[p];
            float4 w4 = *(const float4*)&Wo_c[(size_t)p * BSZ + j0];
            add.x += o * w4.x; add.y += o * w4.y;
            add.z += o * w4.z; add.w += o * w4.w;
          }
          hv4.x = hnewl[li] + add.x; hv4.y = hnewl[li + 1] + add.y;
          hv4.z = hnewl[li + 2] + add.z; hv4.w = hnewl[li + 3] + add.w;
          astore(&h[base], hv4.x);     astore(&h[base + 1], hv4.y);
          astore(&h[base + 2], hv4.z); astore(&h[base + 3], hv4.w);
          astore(&c[base], aload(&cnew[base]));
          astore(&c[base + 1], aload(&cnew[base + 1]));
          astore(&c[base + 2], aload(&cnew[base + 2]));
          astore(&c[base + 3], aload(&cnew[base + 3]));
        } else {
          hv4 = *(float4*)&holdl[li];
        }
        *(float4*)&out[((size_t)t * BS + b) * NHID + li] = hv4;
      }
    }
    gbar2(flags, gen, 2u * t + 2u);
  }
}

__global__ void k_sentinel(float* out) { out[0] = 12345.0f; }

extern "C" void kernel_launch(void* const* d_in, const int* in_sizes, int n_in,
                              void* d_out, int out_size, void* d_ws, size_t ws_size,
                              hipStream_t stream) {
  (void)in_sizes; (void)n_in; (void)out_size;
  const float* x      = (const float*)d_in[0];
  const float* h0     = (const float*)d_in[1];
  const float* c0     = (const float*)d_in[2];
  const float* W_enc  = (const float*)d_in[3];
  const float* b_enc  = (const float*)d_in[4];
  const float* Wq     = (const float*)d_in[5];
  const float* Wk     = (const float*)d_in[6];
  const float* Wv     = (const float*)d_in[7];
  const float* Wi     = (const float*)d_in[8];
  const float* Wh     = (const float*)d_in[9];
  const float* b_lstm = (const float*)d_in[10];
  const float* Wq_c   = (const float*)d_in[11];
  const float* Wk_c   = (const float*)d_in[12];
  const float* Wv_c   = (const float*)d_in[13];
  const float* Wo_c   = (const float*)d_in[14];
  float* out = (float*)d_out;

  float* ws = (float*)d_ws;
  size_t off = 0;
  auto alloc = [&](size_t nf) { float* p = ws + off; off += (nf + 15) & ~(size_t)15; return p; };
  float* k1v1 = alloc((size_t)T_STEPS * BS * KV1);
  float* Wc   = alloc((size_t)NTOKEN * KV1);
  float* bias = alloc(KV1);
  float* Wf   = alloc((size_t)NB * KSUM * GATES);
  float* bf   = alloc((size_t)NB * GATES);
  float* h    = alloc((size_t)BS * NHID);
  float* c    = alloc((size_t)BS * NHID);
  float* hnew = alloc((size_t)BS * NHID);
  float* cnew = alloc((size_t)BS * NHID);
  float* zbuf = alloc((size_t)BS * NB);
  // barrier region: 256 flag lines (16 u32 each) + 8 gen lines
  unsigned* bar = (unsigned*)(ws + off); off += 4096 + 128 + 16;

  if (ws_size < off * sizeof(float)) {  // loud failure instead of OOB corruption
    hipLaunchKernelGGL(k_sentinel, dim3(1), dim3(1), 0, stream, out);
    return;
  }

  hipMemsetAsync(bar, 0, (4096 + 128) * sizeof(unsigned), stream);
  hipMemcpyAsync(h, h0, (size_t)BS * NHID * sizeof(float), hipMemcpyDeviceToDevice, stream);
  hipMemcpyAsync(c, c0, (size_t)BS * NHID * sizeof(float), hipMemcpyDeviceToDevice, stream);

  hipLaunchKernelGGL(k_wc,   dim3(NTOKEN + 1),       dim3(128), 0, stream, W_enc, b_enc, Wk, Wv, Wc, bias);
  hipLaunchKernelGGL(k_kv,   dim3(T_STEPS * BS / 8), dim3(256), 0, stream, x, Wc, bias, k1v1);
  hipLaunchKernelGGL(k_fuse, dim3(NB * KSUM),        dim3(256), 0, stream, Wi, Wh, b_lstm, Wf, bf);
  hipLaunchKernelGGL(k_rnn,  dim3(NWG),              dim3(512), 0, stream,
                     k1v1, Wf, bf, Wq, Wq_c, Wk_c, Wv_c, Wo_c,
                     h, c, hnew, cnew, zbuf, bar, out);
}

// Round 5
// 17686.032 us; speedup vs baseline: 1.7496x; 1.0358x over previous
//
#include <hip/hip_runtime.h>
#include <hip/hip_bf16.h>

#define T_STEPS 256
#define BS      64
#define NTOKEN  512
#define NINP    512
#define NHID    2048
#define NB      8
#define TOPKN   4
#define BSZ     256
#define ATT_OUT 340
#define DK      64
#define NH_C    4
#define DK_C    32
#define KSUM    (ATT_OUT + BSZ)   // 596
#define KV1     (DK + ATT_OUT)    // 404
#define GATES   1024
#define NWG     256

#define AGENT __HIP_MEMORY_SCOPE_AGENT

__device__ __forceinline__ float sigf(float x) { return 1.0f / (1.0f + expf(-x)); }
__device__ __forceinline__ float aload(const float* p) {
  return __hip_atomic_load(p, __ATOMIC_RELAXED, AGENT);
}
__device__ __forceinline__ void astore(float* p, float v) {
  __hip_atomic_store(p, v, __ATOMIC_RELAXED, AGENT);
}
__device__ __forceinline__ unsigned aloadu(const unsigned* p) {
  return __hip_atomic_load(p, __ATOMIC_RELAXED, AGENT);
}
__device__ __forceinline__ void astoreu(unsigned* p, unsigned v) {
  __hip_atomic_store(p, v, __ATOMIC_RELAXED, AGENT);
}

// Distributed-arrival grid barrier (round-2 proven).
__device__ __forceinline__ void gbar2(unsigned* flags, unsigned* gen, unsigned e) {
  const int w = blockIdx.x, tid = threadIdx.x;
  asm volatile("s_waitcnt vmcnt(0) lgkmcnt(0)" ::: "memory");
  __syncthreads();
  if (tid == 0) astoreu(&flags[w * 16], e);
  if (w == NWG - 1) {
    if (tid < NWG) {
      while (aloadu(&flags[tid * 16]) < e) __builtin_amdgcn_s_sleep(1);
    }
    __syncthreads();
    if (tid < 8) astoreu(&gen[tid * 16], e);
  } else {
    if (tid == 0) {
      while (aloadu(&gen[(w & 7) * 16]) < e) __builtin_amdgcn_s_sleep(1);
    }
  }
  __syncthreads();
}

// ---------- Precompute 1: Wc = W_enc @ [Wk | Wv]  (512 x 404), bias_kv = b_enc @ [Wk|Wv]
__global__ void k_wc(const float* __restrict__ W_enc, const float* __restrict__ b_enc,
                     const float* __restrict__ Wk, const float* __restrict__ Wv,
                     float* __restrict__ Wc, float* __restrict__ bias_kv) {
  __shared__ float row[NINP];
  int d = blockIdx.x;  // 0..511 rows, 512 = bias row
  const float* src = (d < NTOKEN) ? (W_enc + (size_t)d * NINP) : b_enc;
  for (int i = threadIdx.x; i < NINP; i += blockDim.x) row[i] = src[i];
  __syncthreads();
  float* dst = (d < NTOKEN) ? (Wc + (size_t)d * KV1) : bias_kv;
  for (int j = threadIdx.x; j < KV1; j += blockDim.x) {
    float acc = 0.f;
    if (j < DK) {
      for (int p = 0; p < NINP; ++p) acc += row[p] * Wk[(size_t)p * DK + j];
    } else {
      int jj = j - DK;
      for (int p = 0; p < NINP; ++p) acc += row[p] * Wv[(size_t)p * ATT_OUT + jj];
    }
    dst[j] = acc;
  }
}

// ---------- Precompute 2: k1v1[t,b,:] = x[t,b,:] @ Wc + bias   (16384 x 404)
__global__ void k_kv(const float* __restrict__ x, const float* __restrict__ Wc,
                     const float* __restrict__ bias_kv, float* __restrict__ k1v1) {
  __shared__ float xl[8 * NTOKEN];
  int r0 = blockIdx.x * 8;
  for (int i = threadIdx.x; i < 8 * NTOKEN; i += blockDim.x)
    xl[i] = x[(size_t)r0 * NTOKEN + i];
  __syncthreads();
  for (int j = threadIdx.x; j < KV1; j += blockDim.x) {
    float bj = bias_kv[j];
    float acc[8];
#pragma unroll
    for (int r = 0; r < 8; ++r) acc[r] = bj;
    for (int d = 0; d < NTOKEN; ++d) {
      float wc = Wc[(size_t)d * KV1 + j];
#pragma unroll
      for (int r = 0; r < 8; ++r) acc[r] += xl[r * NTOKEN + d] * wc;
    }
    for (int r = 0; r < 8; ++r) k1v1[(size_t)(r0 + r) * KV1 + j] = acc[r];
  }
}

// ---------- Precompute 3: gate-interleaved fused weights
__global__ void k_fuse(const float* __restrict__ Wi, const float* __restrict__ Wh,
                       const float* __restrict__ b_lstm,
                       float* __restrict__ Wf, float* __restrict__ bf) {
  int nk = blockIdx.x;  // 8*596
  int n = nk / KSUM, k = nk % KSUM;
  const float* src = (k < ATT_OUT) ? (Wi + ((size_t)n * ATT_OUT + k) * GATES)
                                   : (Wh + ((size_t)n * BSZ + (k - ATT_OUT)) * GATES);
  float* dst = Wf + ((size_t)n * KSUM + k) * GATES;
  for (int gc = threadIdx.x; gc < GATES; gc += blockDim.x) {
    int t = gc >> 8, j = gc & 255;
    dst[j * 4 + t] = src[gc];
  }
  if (k == 0) {
    for (int gc = threadIdx.x; gc < GATES; gc += blockDim.x) {
      int t = gc >> 8, j = gc & 255;
      bf[(size_t)n * GATES + j * 4 + t] = b_lstm[(size_t)n * GATES + gc];
    }
  }
}

// ---------- Main persistent RNN kernel: 256 WGs x 1024 threads (16 waves/CU)
// Phase A GEMM: thread = (kh8, bo, jj) -> 4 batches x 4 gates, K interleaved 8-way.
__global__ __launch_bounds__(1024)
void k_rnn(const float* __restrict__ k1v1, const float* __restrict__ Wf,
           const float* __restrict__ bf, const float* __restrict__ Wq,
           const float* __restrict__ Wq_c, const float* __restrict__ Wk_c,
           const float* __restrict__ Wv_c, const float* __restrict__ Wo_c,
           float* h, float* c, float* hnew, float* cnew, float* zbuf,
           unsigned* bar, float* __restrict__ out) {
  const int w   = blockIdx.x;       // 256 WGs: w = bg*64 + csg*8 + n
  const int tid = threadIdx.x;      // 1024
  const int n   = w & 7;            // block -> XCD (w%8), weights L2-resident
  const int csg = (w >> 3) & 7;     // 32-cell slice
  const int bg  = w >> 6;           // batch group of 16
  const int jj  = tid & 31;         // cell within slice
  const int bo  = (tid >> 5) & 3;   // batch quad (4 batches)
  const int kh8 = tid >> 7;         // K interleave class (k4 % 32 == kh8*4)
  const int jg  = csg * 32 + jj;

  unsigned* flags = bar;
  unsigned* gen   = bar + 4096;

  __shared__ __align__(16) char smem[49152];

  for (int t = 0; t < T_STEPS; ++t) {
    // ================= PHASE A =================
    float (*Al)[600] = (float(*)[600])smem;          // [16][600]: [0:340)=att1*v1, [340:596)=h
    float* k1l  = (float*)(smem + 38400);            // [16][64]
    float* ql   = (float*)(smem + 42496);            // [16][64]
    float* attl = (float*)(smem + 46592);            // [16]

#pragma unroll
    for (int r = 0; r < 4; ++r) {
      int i = r * 1024 + tid;
      int bb = i >> 8, d = i & 255;
      Al[bb][ATT_OUT + d] = aload(&h[(size_t)(bg * 16 + bb) * NHID + n * BSZ + d]);
    }
    if (tid < 256) {
      int bb = tid >> 4, q = tid & 15;
      *(float4*)&k1l[bb * 64 + q * 4] =
          *(const float4*)&k1v1[((size_t)t * BS + bg * 16 + bb) * KV1 + q * 4];
    }
    __syncthreads();
    {  // q = h_n @ Wq : 16x64, 1 per thread
      int bb = tid >> 6, dk = tid & 63;
      float a0 = 0.f;
      const float* hb = &Al[bb][ATT_OUT];
#pragma unroll 4
      for (int d = 0; d < BSZ; ++d)
        a0 += hb[d] * Wq[(size_t)d * DK + dk];
      ql[bb * 64 + dk] = a0;
    }
    __syncthreads();
    if (tid < 256) {  // z: 16 lanes per batch, shfl tree
      int bb = tid >> 4, sub = tid & 15;
      float acc = 0.f;
#pragma unroll
      for (int u = 0; u < 4; ++u)
        acc += ql[bb * 64 + sub * 4 + u] * k1l[bb * 64 + sub * 4 + u];
      acc += __shfl_xor(acc, 1, 64);
      acc += __shfl_xor(acc, 2, 64);
      acc += __shfl_xor(acc, 4, 64);
      acc += __shfl_xor(acc, 8, 64);
      if (sub == 0) {
        float z = acc * 0.125f;
        attl[bb] = sigf(z);
        if (csg == 0) astore(&zbuf[(size_t)(bg * 16 + bb) * NB + n], z);
      }
    }
    __syncthreads();
    for (int i = tid; i < 16 * 85; i += 1024) {  // att1 * v1, float4
      int bb = i / 85, q = i - bb * 85;
      float4 v4 = *(const float4*)&k1v1[((size_t)t * BS + bg * 16 + bb) * KV1 + DK + q * 4];
      float a = attl[bb];
      float4 r;
      r.x = a * v4.x; r.y = a * v4.y; r.z = a * v4.z; r.w = a * v4.w;
      *(float4*)&Al[bb][q * 4] = r;
    }
    __syncthreads();

    // ===== GEMM: 4 batches x 4 gates per thread, K interleaved 8-way =====
    float4 acc[4];
#pragma unroll
    for (int i = 0; i < 4; ++i) acc[i] = make_float4(0.f, 0.f, 0.f, 0.f);
    {
      const float* Wr = Wf + (size_t)n * KSUM * GATES + jg * 4;
      const float* A0 = Al[bo * 4 + 0];
      const float* A1 = Al[bo * 4 + 1];
      const float* A2 = Al[bo * 4 + 2];
      const float* A3 = Al[bo * 4 + 3];
#pragma unroll 4
      for (int k4 = kh8 * 4; k4 < KSUM; k4 += 32) {
        const float* wp = Wr + (size_t)k4 * GATES;
        float4 w0 = *(const float4*)(wp);
        float4 w1 = *(const float4*)(wp + GATES);
        float4 w2 = *(const float4*)(wp + 2 * GATES);
        float4 w3 = *(const float4*)(wp + 3 * GATES);
        float4 a0 = *(const float4*)(A0 + k4);
        float4 a1 = *(const float4*)(A1 + k4);
        float4 a2 = *(const float4*)(A2 + k4);
        float4 a3 = *(const float4*)(A3 + k4);
        acc[0].x += a0.x * w0.x + a0.y * w1.x + a0.z * w2.x + a0.w * w3.x;
        acc[0].y += a0.x * w0.y + a0.y * w1.y + a0.z * w2.y + a0.w * w3.y;
        acc[0].z += a0.x * w0.z + a0.y * w1.z + a0.z * w2.z + a0.w * w3.z;
        acc[0].w += a0.x * w0.w + a0.y * w1.w + a0.z * w2.w + a0.w * w3.w;
        acc[1].x += a1.x * w0.x + a1.y * w1.x + a1.z * w2.x + a1.w * w3.x;
        acc[1].y += a1.x * w0.y + a1.y * w1.y + a1.z * w2.y + a1.w * w3.y;
        acc[1].z += a1.x * w0.z + a1.y * w1.z + a1.z * w2.z + a1.w * w3.z;
        acc[1].w += a1.x * w0.w + a1.y * w1.w + a1.z * w2.w + a1.w * w3.w;
        acc[2].x += a2.x * w0.x + a2.y * w1.x + a2.z * w2.x + a2.w * w3.x;
        acc[2].y += a2.x * w0.y + a2.y * w1.y + a2.z * w2.y + a2.w * w3.y;
        acc[2].z += a2.x * w0.z + a2.y * w1.z + a2.z * w2.z + a2.w * w3.z;
        acc[2].w += a2.x * w0.w + a2.y * w1.w + a2.z * w2.w + a2.w * w3.w;
        acc[3].x += a3.x * w0.x + a3.y * w1.x + a3.z * w2.x + a3.w * w3.x;
        acc[3].y += a3.x * w0.y + a3.y * w1.y + a3.z * w2.y + a3.w * w3.y;
        acc[3].z += a3.x * w0.z + a3.y * w1.z + a3.z * w2.z + a3.w * w3.z;
        acc[3].w += a3.x * w0.w + a3.y * w1.w + a3.z * w2.w + a3.w * w3.w;
      }
    }
    __syncthreads();  // Al dead; red aliases it

    // ===== 8-way kh reduction (2 passes) + LSTM pointwise =====
    {
      float4* red4 = (float4*)smem;  // 32KB over dead Al
#pragma unroll
      for (int p = 0; p < 2; ++p) {
        red4[tid * 2 + 0] = acc[2 * p + 0];
        red4[tid * 2 + 1] = acc[2 * p + 1];
        __syncthreads();
        if (tid < 256) {
          const int bo_r = tid >> 6, q = (tid >> 5) & 1, jjr = tid & 31;
          float4 g4 = make_float4(0.f, 0.f, 0.f, 0.f);
#pragma unroll
          for (int kh = 0; kh < 8; ++kh) {
            float4 v = red4[((kh << 7) + (bo_r << 5) + jjr) * 2 + q];
            g4.x += v.x; g4.y += v.y; g4.z += v.z; g4.w += v.w;
          }
          const int b = bo_r * 4 + 2 * p + q;
          const int jgr = csg * 32 + jjr;
          float4 bia = *(const float4*)&bf[(size_t)n * GATES + jgr * 4];
          float ig = sigf(g4.x + bia.x), fg = sigf(g4.y + bia.y);
          float gg = tanhf(g4.z + bia.z), og = sigf(g4.w + bia.w);
          size_t idx = (size_t)(bg * 16 + b) * NHID + n * BSZ + jgr;
          float cn = fg * aload(&c[idx]) + ig * gg;
          float hn = og * tanhf(cn);
          astore(&cnew[idx], cn);
          astore(&hnew[idx], hn);
        }
        __syncthreads();
      }
    }
    gbar2(flags, gen, 2u * t + 1u);

    // ================= PHASE B (WGs 0..63, one batch each) =================
    if (w < BS) {
      const int b = w;
      float* hnewl = (float*)smem;              // 2048
      float* holdl = (float*)(smem + 8192);     // 2048
      float* qcl   = (float*)(smem + 16384);    // 1024
      float* kcl   = (float*)(smem + 20480);
      float* vcl   = (float*)(smem + 24576);
      float* ocl   = (float*)(smem + 28672);
      float* acl   = (float*)(smem + 32768);    // [4][8][8]
      float* maskl = (float*)(smem + 33792);    // 8

#pragma unroll
      for (int r = 0; r < 2; ++r) {
        int i = r * 1024 + tid;
        hnewl[i] = aload(&hnew[(size_t)b * NHID + i]);
        holdl[i] = aload(&h[(size_t)b * NHID + i]);
      }
      if (tid == 0) {
        // top-4 largest z (== smallest sigmoid(-z)); ties -> lowest index
        float zv[NB];
        for (int k = 0; k < NB; ++k) zv[k] = aload(&zbuf[(size_t)b * NB + k]);
        bool used[NB] = {};
        for (int k = 0; k < NB; ++k) maskl[k] = 0.f;
        for (int s = 0; s < TOPKN; ++s) {
          int best = -1; float bv = 0.f;
          for (int k = 0; k < NB; ++k)
            if (!used[k] && (best < 0 || zv[k] > bv)) { best = k; bv = zv[k]; }
          used[best] = true; maskl[best] = 1.f;
        }
      }
      __syncthreads();
      // qc/kc/vc = hnew @ W*_c : 768 float4 outputs, one per thread
      if (tid < 768) {
        int mat = tid >> 8, r = tid & 255;
        int nn = r >> 5, c0 = (r & 31) * 4;
        const float* W = (mat == 0) ? Wq_c : (mat == 1) ? Wk_c : Wv_c;
        const float* hv = &hnewl[nn * BSZ];
        float4 a4 = make_float4(0.f, 0.f, 0.f, 0.f);
#pragma unroll 4
        for (int d = 0; d < BSZ; ++d) {
          float hb = hv[d];
          float4 w4 = *(const float4*)&W[(size_t)d * 128 + c0];
          a4.x += hb * w4.x; a4.y += hb * w4.y;
          a4.z += hb * w4.z; a4.w += hb * w4.w;
        }
        float* dst = (mat == 0) ? qcl : (mat == 1) ? kcl : vcl;
        *(float4*)&dst[r * 4] = a4;
      }
      __syncthreads();
      if (tid < 32) {  // per (head, nq): softmax over 8 blocks
        int hh = tid >> 3, nq = tid & 7;
        const float* qrow = &qcl[nq * 128 + hh * 32];
        float sc[NB]; float mx = -1e30f;
        for (int m = 0; m < NB; ++m) {
          const float* krow = &kcl[m * 128 + hh * 32];
          float a = 0.f;
#pragma unroll
          for (int kk = 0; kk < DK_C; ++kk) a += qrow[kk] * krow[kk];
          a *= 0.17677669529663687f; sc[m] = a; mx = fmaxf(mx, a);
        }
        float sum = 0.f;
        for (int m = 0; m < NB; ++m) { sc[m] = expf(sc[m] - mx); sum += sc[m]; }
        float inv = 1.f / sum;
        for (int m = 0; m < NB; ++m) acl[(hh * 8 + nq) * 8 + m] = sc[m] * inv;
      }
      __syncthreads();
      if (tid < 256) {  // oc = ac @ vc : 256 float4
        int nn = tid >> 5, c4 = tid & 31, c0 = c4 * 4, hh = c4 >> 3;
        const float* arow = &acl[(hh * 8 + nn) * 8];
        float4 a4 = make_float4(0.f, 0.f, 0.f, 0.f);
#pragma unroll
        for (int m = 0; m < NB; ++m) {
          float a = arow[m];
          float4 v4 = *(const float4*)&vcl[m * 128 + c0];
          a4.x += a * v4.x; a4.y += a * v4.y;
          a4.z += a * v4.z; a4.w += a * v4.w;
        }
        *(float4*)&ocl[tid * 4] = a4;
      }
      __syncthreads();
      if (tid < 512) {  // commit: one float4 of cells per thread
        int nn = tid >> 6, j0 = (tid & 63) * 4;
        int li = nn * BSZ + j0;
        size_t base = (size_t)b * NHID + li;
        float4 hv4;
        if (maskl[nn] > 0.5f) {
          const float* oc = &ocl[nn * 128];
          float4 add = make_float4(0.f, 0.f, 0.f, 0.f);
#pragma unroll 4
          for (int p = 0; p < 128; ++p) {
            float o = oc[p];
            float4 w4 = *(const float4*)&Wo_c[(size_t)p * BSZ + j0];
            add.x += o * w4.x; add.y += o * w4.y;
            add.z += o * w4.z; add.w += o * w4.w;
          }
          hv4.x = hnewl[li] + add.x; hv4.y = hnewl[li + 1] + add.y;
          hv4.z = hnewl[li + 2] + add.z; hv4.w = hnewl[li + 3] + add.w;
          astore(&h[base], hv4.x);     astore(&h[base + 1], hv4.y);
          astore(&h[base + 2], hv4.z); astore(&h[base + 3], hv4.w);
          astore(&c[base], aload(&cnew[base]));
          astore(&c[base + 1], aload(&cnew[base + 1]));
          astore(&c[base + 2], aload(&cnew[base + 2]));
          astore(&c[base + 3], aload(&cnew[base + 3]));
        } else {
          hv4 = *(float4*)&holdl[li];
        }
        *(float4*)&out[((size_t)t * BS + b) * NHID + li] = hv4;
      }
    }
    gbar2(flags, gen, 2u * t + 2u);
  }
}

__global__ void k_sentinel(float* out) { out[0] = 12345.0f; }

extern "C" void kernel_launch(void* const* d_in, const int* in_sizes, int n_in,
                              void* d_out, int out_size, void* d_ws, size_t ws_size,
                              hipStream_t stream) {
  (void)in_sizes; (void)n_in; (void)out_size;
  const float* x      = (const float*)d_in[0];
  const float* h0     = (const float*)d_in[1];
  const float* c0     = (const float*)d_in[2];
  const float* W_enc  = (const float*)d_in[3];
  const float* b_enc  = (const float*)d_in[4];
  const float* Wq     = (const float*)d_in[5];
  const float* Wk     = (const float*)d_in[6];
  const float* Wv     = (const float*)d_in[7];
  const float* Wi     = (const float*)d_in[8];
  const float* Wh     = (const float*)d_in[9];
  const float* b_lstm = (const float*)d_in[10];
  const float* Wq_c   = (const float*)d_in[11];
  const float* Wk_c   = (const float*)d_in[12];
  const float* Wv_c   = (const float*)d_in[13];
  const float* Wo_c   = (const float*)d_in[14];
  float* out = (float*)d_out;

  float* ws = (float*)d_ws;
  size_t off = 0;
  auto alloc = [&](size_t nf) { float* p = ws + off; off += (nf + 15) & ~(size_t)15; return p; };
  float* k1v1 = alloc((size_t)T_STEPS * BS * KV1);
  float* Wc   = alloc((size_t)NTOKEN * KV1);
  float* bias = alloc(KV1);
  float* Wf   = alloc((size_t)NB * KSUM * GATES);
  float* bf   = alloc((size_t)NB * GATES);
  float* h    = alloc((size_t)BS * NHID);
  float* c    = alloc((size_t)BS * NHID);
  float* hnew = alloc((size_t)BS * NHID);
  float* cnew = alloc((size_t)BS * NHID);
  float* zbuf = alloc((size_t)BS * NB);
  // barrier region: 256 flag lines (16 u32 each) + 8 gen lines
  unsigned* bar = (unsigned*)(ws + off); off += 4096 + 128 + 16;

  if (ws_size < off * sizeof(float)) {  // loud failure instead of OOB corruption
    hipLaunchKernelGGL(k_sentinel, dim3(1), dim3(1), 0, stream, out);
    return;
  }

  hipMemsetAsync(bar, 0, (4096 + 128) * sizeof(unsigned), stream);
  hipMemcpyAsync(h, h0, (size_t)BS * NHID * sizeof(float), hipMemcpyDeviceToDevice, stream);
  hipMemcpyAsync(c, c0, (size_t)BS * NHID * sizeof(float), hipMemcpyDeviceToDevice, stream);

  hipLaunchKernelGGL(k_wc,   dim3(NTOKEN + 1),       dim3(128), 0, stream, W_enc, b_enc, Wk, Wv, Wc, bias);
  hipLaunchKernelGGL(k_kv,   dim3(T_STEPS * BS / 8), dim3(256), 0, stream, x, Wc, bias, k1v1);
  hipLaunchKernelGGL(k_fuse, dim3(NB * KSUM),        dim3(256), 0, stream, Wi, Wh, b_lstm, Wf, bf);
  hipLaunchKernelGGL(k_rnn,  dim3(NWG),              dim3(1024), 0, stream,
                     k1v1, Wf, bf, Wq, Wq_c, Wk_c, Wv_c, Wo_c,
                     h, c, hnew, cnew, zbuf, bar, out);
}

// Round 6
// 13742.647 us; speedup vs baseline: 2.2517x; 1.2869x over previous
//
#include <hip/hip_runtime.h>
#include <hip/hip_bf16.h>

#define T_STEPS 256
#define BS      64
#define NTOKEN  512
#define NINP    512
#define NHID    2048
#define NB      8
#define TOPKN   4
#define BSZ     256
#define ATT_OUT 340
#define DK      64
#define NH_C    4
#define DK_C    32
#define KSUM    (ATT_OUT + BSZ)   // 596
#define KV1     (DK + ATT_OUT)    // 404
#define RV      596               // k1v1 row: [v1 0..340) [wk 340..596)
#define GATES   1024
#define NWG     256

#define AGENT __HIP_MEMORY_SCOPE_AGENT

__device__ __forceinline__ float sigf(float x) { return 1.0f / (1.0f + expf(-x)); }
__device__ __forceinline__ float aload(const float* p) {
  return __hip_atomic_load(p, __ATOMIC_RELAXED, AGENT);
}
__device__ __forceinline__ void astore(float* p, float v) {
  __hip_atomic_store(p, v, __ATOMIC_RELAXED, AGENT);
}
__device__ __forceinline__ unsigned aloadu(const unsigned* p) {
  return __hip_atomic_load(p, __ATOMIC_RELAXED, AGENT);
}
__device__ __forceinline__ void astoreu(unsigned* p, unsigned v) {
  __hip_atomic_store(p, v, __ATOMIC_RELAXED, AGENT);
}

__device__ __forceinline__ void gfma(float4& acc, const float4& a4, const float4& w0,
                                     const float4& w1, const float4& w2, const float4& w3) {
  acc.x += a4.x * w0.x + a4.y * w1.x + a4.z * w2.x + a4.w * w3.x;
  acc.y += a4.x * w0.y + a4.y * w1.y + a4.z * w2.y + a4.w * w3.y;
  acc.z += a4.x * w0.z + a4.y * w1.z + a4.z * w2.z + a4.w * w3.z;
  acc.w += a4.x * w0.w + a4.y * w1.w + a4.z * w2.w + a4.w * w3.w;
}
__device__ __forceinline__ void sfma(float4& acc, float s, const float4& w) {
  acc.x += s * w.x; acc.y += s * w.y; acc.z += s * w.z; acc.w += s * w.w;
}

// Distributed-arrival grid barrier (round-2 proven).
__device__ __forceinline__ void gbar2(unsigned* flags, unsigned* gen, unsigned e) {
  const int w = blockIdx.x, tid = threadIdx.x;
  asm volatile("s_waitcnt vmcnt(0) lgkmcnt(0)" ::: "memory");
  __syncthreads();
  if (tid == 0) astoreu(&flags[w * 16], e);
  if (w == NWG - 1) {
    if (tid < NWG) {
      while (aloadu(&flags[tid * 16]) < e) __builtin_amdgcn_s_sleep(1);
    }
    __syncthreads();
    if (tid < 8) astoreu(&gen[tid * 16], e);
  } else {
    if (tid == 0) {
      while (aloadu(&gen[(w & 7) * 16]) < e) __builtin_amdgcn_s_sleep(1);
    }
  }
  __syncthreads();
}

// ---------- Precompute 1: Wc = W_enc @ [Wk | Wv], bias_kv = b_enc @ [Wk|Wv]
__global__ void k_wc(const float* __restrict__ W_enc, const float* __restrict__ b_enc,
                     const float* __restrict__ Wk, const float* __restrict__ Wv,
                     float* __restrict__ Wc, float* __restrict__ bias_kv) {
  __shared__ float row[NINP];
  int d = blockIdx.x;
  const float* src = (d < NTOKEN) ? (W_enc + (size_t)d * NINP) : b_enc;
  for (int i = threadIdx.x; i < NINP; i += blockDim.x) row[i] = src[i];
  __syncthreads();
  float* dst = (d < NTOKEN) ? (Wc + (size_t)d * KV1) : bias_kv;
  for (int j = threadIdx.x; j < KV1; j += blockDim.x) {
    float acc = 0.f;
    if (j < DK) {
      for (int p = 0; p < NINP; ++p) acc += row[p] * Wk[(size_t)p * DK + j];
    } else {
      int jj = j - DK;
      for (int p = 0; p < NINP; ++p) acc += row[p] * Wv[(size_t)p * ATT_OUT + jj];
    }
    dst[j] = acc;
  }
}

// ---------- Precompute 2: k1v1[t,b] = [v1 | wk] with v1 = xt@Wv-part, wk = Wq @ k1
__global__ void k_kv(const float* __restrict__ x, const float* __restrict__ Wc,
                     const float* __restrict__ bias_kv, const float* __restrict__ Wq,
                     float* __restrict__ k1v1) {
  __shared__ float xl[8 * NTOKEN];
  __shared__ float k1s[8 * DK];
  int r0 = blockIdx.x * 8;
  for (int i = threadIdx.x; i < 8 * NTOKEN; i += blockDim.x)
    xl[i] = x[(size_t)r0 * NTOKEN + i];
  __syncthreads();
  for (int j = threadIdx.x; j < KV1; j += 256) {
    float bj = bias_kv[j];
    float acc[8];
#pragma unroll
    for (int r = 0; r < 8; ++r) acc[r] = bj;
    for (int d = 0; d < NTOKEN; ++d) {
      float wc = Wc[(size_t)d * KV1 + j];
#pragma unroll
      for (int r = 0; r < 8; ++r) acc[r] += xl[r * NTOKEN + d] * wc;
    }
    if (j < DK) {
#pragma unroll
      for (int r = 0; r < 8; ++r) k1s[r * DK + j] = acc[r];
    } else {
#pragma unroll
      for (int r = 0; r < 8; ++r) k1v1[(size_t)(r0 + r) * RV + (j - DK)] = acc[r];
    }
  }
  __syncthreads();
  {  // wk[r][d] = sum_dk k1[r][dk] * Wq[d][dk]   (256 threads, d = tid)
    int d = threadIdx.x;
    float a[8];
#pragma unroll
    for (int r = 0; r < 8; ++r) a[r] = 0.f;
    for (int dk4 = 0; dk4 < 16; ++dk4) {
      float4 w4 = *(const float4*)&Wq[(size_t)d * DK + dk4 * 4];
#pragma unroll
      for (int r = 0; r < 8; ++r) {
        float4 kk = *(const float4*)&k1s[r * DK + dk4 * 4];
        a[r] += kk.x * w4.x + kk.y * w4.y + kk.z * w4.z + kk.w * w4.w;
      }
    }
#pragma unroll
    for (int r = 0; r < 8; ++r) k1v1[(size_t)(r0 + r) * RV + ATT_OUT + d] = a[r];
  }
}

// ---------- Precompute 3: gate-interleaved fused weights
__global__ void k_fuse(const float* __restrict__ Wi, const float* __restrict__ Wh,
                       const float* __restrict__ b_lstm,
                       float* __restrict__ Wf, float* __restrict__ bf) {
  int nk = blockIdx.x;  // 8*596
  int n = nk / KSUM, k = nk % KSUM;
  const float* src = (k < ATT_OUT) ? (Wi + ((size_t)n * ATT_OUT + k) * GATES)
                                   : (Wh + ((size_t)n * BSZ + (k - ATT_OUT)) * GATES);
  float* dst = Wf + ((size_t)n * KSUM + k) * GATES;
  for (int gc = threadIdx.x; gc < GATES; gc += blockDim.x) {
    int t = gc >> 8, j = gc & 255;
    dst[j * 4 + t] = src[gc];
  }
  if (k == 0) {
    for (int gc = threadIdx.x; gc < GATES; gc += blockDim.x) {
      int t = gc >> 8, j = gc & 255;
      bf[(size_t)n * GATES + j * 4 + t] = b_lstm[(size_t)n * GATES + gc];
    }
  }
}

// ---------- Main persistent RNN kernel: 256 WGs x 1024 threads
// LDS (floats): c_cur[512]@0  c_pend[512]@512  zl[128]@1024  attl[16]@1152
//               h_comm[2048]@1168 (B persistent)   scratch @3216 (Al[16][600])
__global__ __launch_bounds__(1024)
void k_rnn(const float* __restrict__ k1v1, const float* __restrict__ Wf,
           const float* __restrict__ bf,
           const float* __restrict__ Wq_c, const float* __restrict__ Wk_c,
           const float* __restrict__ Wv_c, const float* __restrict__ Wo_c,
           const float* __restrict__ c0,
           float* h, float* hnew, float* zbuf,
           unsigned* bar, float* __restrict__ out) {
  const int w   = blockIdx.x;       // w = bg*64 + csg*8 + n
  const int tid = threadIdx.x;      // 1024
  const int n   = w & 7;            // block -> XCD, Wf[n] L2-resident
  const int csg = (w >> 3) & 7;     // 32-cell slice
  const int bg  = w >> 6;           // batch group of 16

  unsigned* flags = bar;
  unsigned* gen   = bar + 4096;

  __shared__ __align__(16) float smem[12816];
  float* c_cur  = smem;            // [16][32] committed c (own slice)
  float* c_pend = smem + 512;      // [16][32] pending c_new
  float* zl     = smem + 1024;     // [16][8]
  float* attl   = smem + 1152;     // [16]
  float* h_comm = smem + 1168;     // [2048] (w<64 only)
  float* Al     = smem + 3216;     // [16][600]

  // init local state
  if (tid < 512) {
    int b = tid >> 5, jj = tid & 31;
    c_cur[tid] = c0[(size_t)(bg * 16 + b) * NHID + n * BSZ + csg * 32 + jj];
  }
  if (w < BS) {
    for (int i = tid; i < NHID; i += 1024) h_comm[i] = aload(&h[(size_t)w * NHID + i]);
  }

  for (int t = 0; t < T_STEPS; ++t) {
    // ===== S1: stage committed h -> Al rows [340,596); zl <- zbuf(t-1) =====
#pragma unroll
    for (int r = 0; r < 4; ++r) {
      int i = r * 1024 + tid;
      int bb = i >> 8, d = i & 255;
      Al[bb * 600 + ATT_OUT + d] = aload(&h[(size_t)(bg * 16 + bb) * NHID + n * BSZ + d]);
    }
    if (tid >= 512 && tid < 640) {
      int q = tid - 512;
      zl[q] = aload(&zbuf[(size_t)(bg * 16 + (q >> 3)) * NB + (q & 7)]);
    }
    __syncthreads();
    // ===== S2: z = (h . wk)/8 per (batch=wave) =====
    {
      int bb = tid >> 6, lane = tid & 63;
      float4 h4  = *(float4*)&Al[bb * 600 + ATT_OUT + lane * 4];
      float4 wk4 = *(const float4*)&k1v1[((size_t)t * BS + bg * 16 + bb) * RV + ATT_OUT + lane * 4];
      float zp = h4.x * wk4.x + h4.y * wk4.y + h4.z * wk4.z + h4.w * wk4.w;
      zp += __shfl_xor(zp, 1);  zp += __shfl_xor(zp, 2);  zp += __shfl_xor(zp, 4);
      zp += __shfl_xor(zp, 8);  zp += __shfl_xor(zp, 16); zp += __shfl_xor(zp, 32);
      if (lane == 0) {
        float z = zp * 0.125f;
        attl[bb] = sigf(z);
        if (csg == 0) astore(&zbuf[(size_t)(bg * 16 + bb) * NB + n], z);
      }
    }
    __syncthreads();
    // ===== S3: Al rows [0,340) = att1 * v1 =====
    for (int i = tid; i < 16 * 85; i += 1024) {
      int bb = i / 85, q = i - bb * 85;
      float4 v4 = *(const float4*)&k1v1[((size_t)t * BS + bg * 16 + bb) * RV + q * 4];
      float a = attl[bb];
      float4 r;
      r.x = a * v4.x; r.y = a * v4.y; r.z = a * v4.z; r.w = a * v4.w;
      *(float4*)&Al[bb * 600 + q * 4] = r;
    }
    __syncthreads();
    // ===== S4: GEMM — thread (kh16, bo2, jj32): 8 batches x 4 gates =====
    const int jjG = tid & 31, boG = (tid >> 5) & 1, khG = tid >> 6;
    float4 acc[8];
#pragma unroll
    for (int i = 0; i < 8; ++i) acc[i] = make_float4(0.f, 0.f, 0.f, 0.f);
    {
      const float* Wr = Wf + (size_t)n * KSUM * GATES + (size_t)(csg * 32 + jjG) * 4;
      const float* Ab = Al + boG * 8 * 600;
#pragma unroll 2
      for (int k4 = khG * 4; k4 < KSUM; k4 += 64) {
        const float* wp = Wr + (size_t)k4 * GATES;
        float4 w0 = *(const float4*)(wp);
        float4 w1 = *(const float4*)(wp + GATES);
        float4 w2 = *(const float4*)(wp + 2 * GATES);
        float4 w3 = *(const float4*)(wp + 3 * GATES);
#pragma unroll
        for (int i = 0; i < 8; ++i) {
          float4 a4 = *(const float4*)&Ab[i * 600 + k4];
          gfma(acc[i], a4, w0, w1, w2, w3);
        }
      }
    }
    __syncthreads();  // Al dead
    // ===== S5: 16-way kh reduction (4 passes) + c-commit + LSTM =====
    {
      float4* red4 = (float4*)Al;
#pragma unroll
      for (int p = 0; p < 4; ++p) {
        red4[khG * 132 + boG * 64 + jjG * 2 + 0] = acc[2 * p];
        red4[khG * 132 + boG * 64 + jjG * 2 + 1] = acc[2 * p + 1];
        __syncthreads();
        if (tid < 128) {
          int rb = tid >> 5, jjr = tid & 31;
          int bo_r = rb >> 1, q_r = rb & 1;
          int batch = bo_r * 8 + 2 * p + q_r;
          float4 g4 = make_float4(0.f, 0.f, 0.f, 0.f);
#pragma unroll
          for (int kh = 0; kh < 16; ++kh) {
            float4 v = red4[kh * 132 + bo_r * 64 + jjr * 2 + q_r];
            g4.x += v.x; g4.y += v.y; g4.z += v.z; g4.w += v.w;
          }
          int jgr = csg * 32 + jjr;
          float4 bia = *(const float4*)&bf[(size_t)n * GATES + jgr * 4];
          float ig = sigf(g4.x + bia.x), fg = sigf(g4.y + bia.y);
          float gg = tanhf(g4.z + bia.z), og = sigf(g4.w + bia.w);
          // commit c with mask(t-1) (rank over zl; ties -> lowest index)
          float cc = c_cur[batch * 32 + jjr];
          if (t > 0) {
            float zn = zl[batch * 8 + n];
            int rank = 0;
#pragma unroll
            for (int j = 0; j < NB; ++j) {
              float zj = zl[batch * 8 + j];
              rank += (zj > zn || (zj == zn && j < n)) ? 1 : 0;
            }
            if (rank < TOPKN) cc = c_pend[batch * 32 + jjr];
          }
          float cn = fg * cc + ig * gg;
          float hn = og * tanhf(cn);
          c_cur[batch * 32 + jjr]  = cc;
          c_pend[batch * 32 + jjr] = cn;
          astore(&hnew[(size_t)(bg * 16 + batch) * NHID + n * BSZ + jgr], hn);
        }
        __syncthreads();
      }
    }
    gbar2(flags, gen, 2u * t + 1u);

    // ===== PHASE B (WGs 0..63, one batch each) =====
    if (w < BS) {
      const int b = w;
      float* hnewl = Al;
      float* qcl   = Al + 2048;
      float* kcl   = Al + 3072;
      float* vcl   = Al + 4096;
      float* ocl   = Al + 5120;
      float* scl   = Al + 6144;   // [4][8][8]
      float* acl   = Al + 6400;   // [4][8][8]
      float* zlB   = Al + 6656;   // [8]

      for (int i = tid; i < NHID; i += 1024)
        hnewl[i] = aload(&hnew[(size_t)b * NHID + i]);
      if (tid >= 1016) zlB[tid - 1016] = aload(&zbuf[(size_t)b * NB + (tid - 1016)]);
      __syncthreads();
      // qkv: tid<768: (mat3, c4 32, kq 8) -> 8 nn accumulators, kq shfl-reduce
      if (tid < 768) {
        int mat = tid >> 8, c4 = (tid >> 3) & 31, kq = tid & 7;
        int c0 = c4 * 4;
        const float* W = (mat == 0) ? Wq_c : (mat == 1) ? Wk_c : Wv_c;
        float4 a8[8];
#pragma unroll
        for (int i = 0; i < 8; ++i) a8[i] = make_float4(0.f, 0.f, 0.f, 0.f);
#pragma unroll 2
        for (int m = 0; m < 8; ++m) {
          int d0 = kq * 4 + 32 * m;   // bank-spread K slices
          float4 w_0 = *(const float4*)&W[(size_t)(d0 + 0) * 128 + c0];
          float4 w_1 = *(const float4*)&W[(size_t)(d0 + 1) * 128 + c0];
          float4 w_2 = *(const float4*)&W[(size_t)(d0 + 2) * 128 + c0];
          float4 w_3 = *(const float4*)&W[(size_t)(d0 + 3) * 128 + c0];
#pragma unroll
          for (int nn = 0; nn < 8; ++nn) {
            float4 h4 = *(const float4*)&hnewl[nn * 256 + d0];
            sfma(a8[nn], h4.x, w_0); sfma(a8[nn], h4.y, w_1);
            sfma(a8[nn], h4.z, w_2); sfma(a8[nn], h4.w, w_3);
          }
        }
#pragma unroll
        for (int mk = 1; mk <= 4; mk <<= 1) {
#pragma unroll
          for (int nn = 0; nn < 8; ++nn) {
            a8[nn].x += __shfl_xor(a8[nn].x, mk);
            a8[nn].y += __shfl_xor(a8[nn].y, mk);
            a8[nn].z += __shfl_xor(a8[nn].z, mk);
            a8[nn].w += __shfl_xor(a8[nn].w, mk);
          }
        }
        if (kq == 0) {
          float* dst = (mat == 0) ? qcl : (mat == 1) ? kcl : vcl;
#pragma unroll
          for (int nn = 0; nn < 8; ++nn)
            *(float4*)&dst[nn * 128 + c0] = a8[nn];
        }
      }
      __syncthreads();
      // scores: tid<256: (hh, nq, m) dot32
      if (tid < 256) {
        int hh = tid >> 6, nq = (tid >> 3) & 7, m = tid & 7;
        const float* qrow = &qcl[nq * 128 + hh * 32];
        const float* krow = &kcl[m * 128 + hh * 32];
        float a = 0.f;
#pragma unroll
        for (int k4 = 0; k4 < 8; ++k4) {
          float4 q4 = *(const float4*)&qrow[k4 * 4];
          float4 k4v = *(const float4*)&krow[k4 * 4];
          a += q4.x * k4v.x + q4.y * k4v.y + q4.z * k4v.z + q4.w * k4v.w;
        }
        scl[tid] = a * 0.17677669529663687f;
      }
      __syncthreads();
      if (tid < 32) {  // softmax rows
        int hh = tid >> 3, nq = tid & 7;
        const float* row = &scl[hh * 64 + nq * 8];
        float mx = -1e30f;
#pragma unroll
        for (int m = 0; m < NB; ++m) mx = fmaxf(mx, row[m]);
        float e[NB]; float sum = 0.f;
#pragma unroll
        for (int m = 0; m < NB; ++m) { e[m] = expf(row[m] - mx); sum += e[m]; }
        float inv = 1.f / sum;
#pragma unroll
        for (int m = 0; m < NB; ++m) acl[(hh * 8 + nq) * 8 + m] = e[m] * inv;
      }
      __syncthreads();
      if (tid < 256) {  // oc = ac @ vc
        int nn = tid >> 5, c4 = tid & 31, c0 = c4 * 4, hh = c4 >> 3;
        const float* arow = &acl[(hh * 8 + nn) * 8];
        float4 a4 = make_float4(0.f, 0.f, 0.f, 0.f);
#pragma unroll
        for (int m = 0; m < NB; ++m) {
          float a = arow[m];
          float4 v4 = *(const float4*)&vcl[m * 128 + c0];
          sfma(a4, a, v4);
        }
        *(float4*)&ocl[tid * 4] = a4;
      }
      __syncthreads();
      if (tid < 512) {  // commit h (LDS h_comm + global h for masked) + out
        int nn = tid >> 6, j0 = (tid & 63) * 4;
        int li = nn * BSZ + j0;
        float zn = zlB[nn];
        int rank = 0;
#pragma unroll
        for (int j = 0; j < NB; ++j) {
          float zj = zlB[j];
          rank += (zj > zn || (zj == zn && j < nn)) ? 1 : 0;
        }
        float4 hv4;
        if (rank < TOPKN) {
          const float* oc = &ocl[nn * 128];
          float4 add = make_float4(0.f, 0.f, 0.f, 0.f);
#pragma unroll 4
          for (int p = 0; p < 128; ++p) {
            float o = oc[p];
            float4 w4 = *(const float4*)&Wo_c[(size_t)p * BSZ + j0];
            sfma(add, o, w4);
          }
          hv4.x = hnewl[li] + add.x;     hv4.y = hnewl[li + 1] + add.y;
          hv4.z = hnewl[li + 2] + add.z; hv4.w = hnewl[li + 3] + add.w;
          *(float4*)&h_comm[li] = hv4;
          size_t base = (size_t)b * NHID + li;
          astore(&h[base], hv4.x);     astore(&h[base + 1], hv4.y);
          astore(&h[base + 2], hv4.z); astore(&h[base + 3], hv4.w);
        } else {
          hv4 = *(float4*)&h_comm[li];
        }
        *(float4*)&out[((size_t)t * BS + b) * NHID + li] = hv4;
      }
    }
    gbar2(flags, gen, 2u * t + 2u);
  }
}

__global__ void k_sentinel(float* out) { out[0] = 12345.0f; }

extern "C" void kernel_launch(void* const* d_in, const int* in_sizes, int n_in,
                              void* d_out, int out_size, void* d_ws, size_t ws_size,
                              hipStream_t stream) {
  (void)in_sizes; (void)n_in; (void)out_size;
  const float* x      = (const float*)d_in[0];
  const float* h0     = (const float*)d_in[1];
  const float* c0     = (const float*)d_in[2];
  const float* W_enc  = (const float*)d_in[3];
  const float* b_enc  = (const float*)d_in[4];
  const float* Wq     = (const float*)d_in[5];
  const float* Wk     = (const float*)d_in[6];
  const float* Wv     = (const float*)d_in[7];
  const float* Wi     = (const float*)d_in[8];
  const float* Wh     = (const float*)d_in[9];
  const float* b_lstm = (const float*)d_in[10];
  const float* Wq_c   = (const float*)d_in[11];
  const float* Wk_c   = (const float*)d_in[12];
  const float* Wv_c   = (const float*)d_in[13];
  const float* Wo_c   = (const float*)d_in[14];
  float* out = (float*)d_out;

  float* ws = (float*)d_ws;
  size_t off = 0;
  auto alloc = [&](size_t nf) { float* p = ws + off; off += (nf + 15) & ~(size_t)15; return p; };
  float* k1v1 = alloc((size_t)T_STEPS * BS * RV);
  float* Wc   = alloc((size_t)NTOKEN * KV1);
  float* bias = alloc(KV1);
  float* Wf   = alloc((size_t)NB * KSUM * GATES);
  float* bf   = alloc((size_t)NB * GATES);
  float* h    = alloc((size_t)BS * NHID);
  float* hnew = alloc((size_t)BS * NHID);
  float* zbuf = alloc((size_t)BS * NB);
  unsigned* bar = (unsigned*)(ws + off); off += 4096 + 128 + 16;

  if (ws_size < off * sizeof(float)) {  // loud failure instead of OOB corruption
    hipLaunchKernelGGL(k_sentinel, dim3(1), dim3(1), 0, stream, out);
    return;
  }

  hipMemsetAsync(bar, 0, (4096 + 128) * sizeof(unsigned), stream);
  hipMemcpyAsync(h, h0, (size_t)BS * NHID * sizeof(float), hipMemcpyDeviceToDevice, stream);

  hipLaunchKernelGGL(k_wc,   dim3(NTOKEN + 1),       dim3(128), 0, stream, W_enc, b_enc, Wk, Wv, Wc, bias);
  hipLaunchKernelGGL(k_kv,   dim3(T_STEPS * BS / 8), dim3(256), 0, stream, x, Wc, bias, Wq, k1v1);
  hipLaunchKernelGGL(k_fuse, dim3(NB * KSUM),        dim3(256), 0, stream, Wi, Wh, b_lstm, Wf, bf);
  hipLaunchKernelGGL(k_rnn,  dim3(NWG),              dim3(1024), 0, stream,
                     k1v1, Wf, bf, Wq_c, Wk_c, Wv_c, Wo_c, c0,
                     h, hnew, zbuf, bar, out);
}